// Round 13
// baseline (1326.667 us; speedup 1.0000x reference)
//
#include <hip/hip_runtime.h>
#include <hip/hip_bf16.h>
#include <math.h>

// Problem constants
#define BB 8
#define TT 2048
#define HH 1024
#define FF 4096
#define EE 8

typedef __attribute__((ext_vector_type(8))) short sh8;   // 8 bf16 (4 VGPRs)
typedef __attribute__((ext_vector_type(4))) short sh4;   // 4 bf16 (8B)
typedef __attribute__((ext_vector_type(4))) float f32x4; // MFMA acc
typedef __attribute__((ext_vector_type(4))) float f4;

__device__ inline unsigned short f2bf(float f) {
  unsigned u = __builtin_bit_cast(unsigned, f);
  u += 0x7FFFu + ((u >> 16) & 1u);
  return (unsigned short)(u >> 16);
}

// A&S 7.1.25 erf approximation, |err| <= 2.5e-5, branchless (3-term).
__device__ inline float erf_fast(float x) {
  float ax = fabsf(x);
  float t = 1.0f / (1.0f + 0.47047f * ax);
  float y = t * (0.3480242f + t * (-0.0958798f + t * 0.7478556f));
  float e = __expf(-ax * ax);
  float r = 1.0f - y * e;
  return copysignf(r, x);
}

// async global->LDS, 16B per lane, wave-uniform LDS base + lane*16
__device__ inline void gload_lds16(const void* g, void* l) {
  __builtin_amdgcn_global_load_lds(
      (const __attribute__((address_space(1))) unsigned int*)g,
      (__attribute__((address_space(3))) unsigned int*)l, 16, 0, 0);
}

// ---------------- fused: X f32 -> bf16 AND per-chunk column partial sums ----------------
__global__ __launch_bounds__(256) void prep(const float* __restrict__ X,
                                            unsigned short* __restrict__ Xb,
                                            float* __restrict__ partial) {
  int tc = blockIdx.x, b = blockIdx.y, t = threadIdx.x;
  const float* src = X + ((size_t)b * TT + (size_t)tc * 128) * HH;
  unsigned short* dst = Xb + ((size_t)b * TT + (size_t)tc * 128) * HH;
  f4 s = {0.f, 0.f, 0.f, 0.f};
  for (int r = 0; r < 128; ++r) {
    f4 v = *(const f4*)&src[(size_t)r * HH + t * 4];
    s[0] += v[0]; s[1] += v[1]; s[2] += v[2]; s[3] += v[3];
    sh4 o;
    o[0] = (short)f2bf(v[0]); o[1] = (short)f2bf(v[1]);
    o[2] = (short)f2bf(v[2]); o[3] = (short)f2bf(v[3]);
    *(sh4*)&dst[(size_t)r * HH + t * 4] = o;
  }
  *(f4*)&partial[((size_t)b * 16 + tc) * HH + t * 4] = s;
}

// ---------------- gating: logits -> softmax -> top2 -> routing ----------------
__global__ __launch_bounds__(256) void gating_kernel(const float* __restrict__ partial,
                                                     const float* __restrict__ gw,
                                                     int* __restrict__ re,
                                                     float* __restrict__ rw) {
  int b = blockIdx.x, t = threadIdx.x;
  float acc[EE];
#pragma unroll
  for (int e = 0; e < EE; e++) acc[e] = 0.f;
  for (int jj = 0; jj < 4; jj++) {
    int h = t + jj * 256;
    float s = 0.f;
    for (int tc = 0; tc < 16; tc++) s += partial[((size_t)b * 16 + tc) * HH + h];
    s *= (1.0f / (float)TT);
#pragma unroll
    for (int e = 0; e < EE; e++) acc[e] += s * gw[h * EE + e];
  }
#pragma unroll
  for (int off = 32; off >= 1; off >>= 1) {
#pragma unroll
    for (int e = 0; e < EE; e++) acc[e] += __shfl_down(acc[e], off);
  }
  __shared__ float red[4][EE];
  if ((t & 63) == 0) {
#pragma unroll
    for (int e = 0; e < EE; e++) red[t >> 6][e] = acc[e];
  }
  __syncthreads();
  if (t == 0) {
    float lg[EE];
#pragma unroll
    for (int e = 0; e < EE; e++) lg[e] = red[0][e] + red[1][e] + red[2][e] + red[3][e];
    float mx = lg[0];
#pragma unroll
    for (int e = 1; e < EE; e++) mx = fmaxf(mx, lg[e]);
    float p[EE]; float s = 0.f;
#pragma unroll
    for (int e = 0; e < EE; e++) { p[e] = expf(lg[e] - mx); s += p[e]; }
#pragma unroll
    for (int e = 0; e < EE; e++) p[e] /= s;
    int i1 = 0;
#pragma unroll
    for (int e = 1; e < EE; e++) if (p[e] > p[i1]) i1 = e;  // first index wins ties
    int i2 = -1;
#pragma unroll
    for (int e = 0; e < EE; e++) {
      if (e == i1) continue;
      if (i2 < 0 || p[e] > p[i2]) i2 = e;
    }
    float den = p[i1] + p[i2];
    re[b * 2 + 0] = i1; rw[b * 2 + 0] = p[i1] / den;
    re[b * 2 + 1] = i2; rw[b * 2 + 1] = p[i2] / den;
  }
}

// ---------------- transpose+convert per-EXPERT weights: W[e][K][N] f32 -> Wt[e][N][K] bf16
// perm=1 (w2): within each K-32 block, stored position c holds logical
// k = (c&32) + (c&1)*16 + ((c>>1)&15) — matching hmid v3's f-permutation so the
// MFMA K-order is consistent between A (hmid) and B (w2t) in MODE1.
__global__ __launch_bounds__(256) void transposeE(const float* __restrict__ W,
                                                  unsigned short* __restrict__ Wt,
                                                  const int* __restrict__ re,
                                                  int K, int N, int perm) {
  int e = blockIdx.z;
  bool u = false;
#pragma unroll
  for (int p = 0; p < 16; p++) u = u || (re[p] == e);
  if (!u) return;

  __shared__ float tile[64][65];
  int kb = blockIdx.x, nb = blockIdx.y;
  const float* src = W + (size_t)e * K * N + (size_t)(kb * 64) * N + nb * 64;
  int t = threadIdx.x;
#pragma unroll
  for (int pass = 0; pass < 4; pass++) {
    int r = (t >> 4) + pass * 16;
    int c = (t & 15) * 4;
    *(f4*)&tile[r][c] = *(const f4*)&src[(size_t)r * N + c];
  }
  __syncthreads();
#pragma unroll
  for (int pass = 0; pass < 2; pass++) {
    int idx = (t + pass * 256) * 8;
    int nl = idx >> 6, k0 = idx & 63;
    sh8 o;
    if (perm) {
#pragma unroll
      for (int j = 0; j < 8; j++) {
        int local = (k0 & 31) + j;
        int kk = (k0 & 32) + ((local & 1) << 4) + (local >> 1);
        o[j] = (short)f2bf(tile[kk][nl]);
      }
    } else {
#pragma unroll
      for (int j = 0; j < 8; j++) o[j] = (short)f2bf(tile[k0 + j][nl]);
    }
    *(sh8*)&Wt[(size_t)e * N * K + (size_t)(nb * 64 + nl) * K + kb * 64 + k0] = o;
  }
}

// ================= 256x256 8-phase counted-vmcnt GEMM (T1+T2+T3+T4+T5) =================
// R13 = R12 (v3 hmid layout, packed 4B nt epilogue stores) + R10's register-safe
// epilogue SLICING, now with the write-allocate mechanism removed (v3 packed nt
// stores cover full 64B lines; R10's explosion was plain scattered 2B stores):
//   seg's last tile-pair (STD8E): EPI(0,0)@ph6, EPI(0,1)@ph7, EPI(1,1)@ph8 — each
//   slice = 16 x 4B nt-stores of a FINALIZED quadrant (finalized at ph5), issued in
//   the phase's STMT; phase-8 wait = vmcnt(36): each of PH3(1)/PH4(1) contributes
//   exactly 18 vmem ops (16 st + 2 ld) so the 36-window spares exactly tile T+3's
//   q0 prefetch, order-robustly; all tile T+2 loads + older stores drain (stores
//   >=1.5 phases old, nt ack << that).
//   next seg's first pair (STD8Z): EPI(1,0)@ph1 (MFMA_CLZ zero-C re-creates
//   quadrants; (1,0) overwritten only at ph4 — no double-liveness, R9's bug).
//   Seg 7: TAIL8E slices in empty phases; EPI(1,0) serial at end.
// MODE 1: unchanged (STD8/TAIL8, serial nt epilogue).
// hmid v3 (elements, per pair): (mb*16+f256)*65536 + wc*16384 + row*64 + c, where
//   logical f = nn*16+ln stored at c = (nn>>1)*32 + ln*2 + (nn&1); w2t carries the
//   identical K-permutation (transposeE perm=1).
// LDS 128KB: A[2][256][64] + B[2][256][64] bf16, XOR swizzle byte ^= (row&7)<<4 via
//   inverse-swizzled GLOBAL SOURCE + swizzled ds_read. Frags read ONCE per tile (24).
// vmcnt ledger: prologue 12 issued, vmcnt(4); steady vmcnt(4) at phases 4/8
//   (STD8E ph8: vmcnt(36)); final tail vmcnt(0) at phase 4.

#define MFMA_CL(qm, qn, BREG)                                                      \
    __builtin_amdgcn_s_setprio(1);                                                 \
    _Pragma("unroll")                                                              \
    for (int m4 = 0; m4 < 4; m4++)                                                 \
      _Pragma("unroll")                                                            \
      for (int n2 = 0; n2 < 2; n2++)                                               \
        _Pragma("unroll")                                                          \
        for (int kk = 0; kk < 2; kk++)                                             \
          acc[(qm) * 4 + m4][(qn) * 2 + n2] =                                      \
              __builtin_amdgcn_mfma_f32_16x16x32_bf16(                             \
                  Aq[m4 * 2 + kk], BREG[n2 * 2 + kk],                              \
                  acc[(qm) * 4 + m4][(qn) * 2 + n2], 0, 0, 0);                     \
    __builtin_amdgcn_s_setprio(0);

// zero-C variant: fresh accumulation (old quadrant value must already be dead)
#define MFMA_CLZ(qm, qn, BREG)                                                     \
    __builtin_amdgcn_s_setprio(1);                                                 \
    _Pragma("unroll")                                                              \
    for (int m4 = 0; m4 < 4; m4++)                                                 \
      _Pragma("unroll")                                                            \
      for (int n2 = 0; n2 < 2; n2++) {                                             \
        f32x4 z0 = {0.f, 0.f, 0.f, 0.f};                                           \
        z0 = __builtin_amdgcn_mfma_f32_16x16x32_bf16(                              \
            Aq[m4 * 2], BREG[n2 * 2], z0, 0, 0, 0);                                \
        acc[(qm) * 4 + m4][(qn) * 2 + n2] =                                        \
            __builtin_amdgcn_mfma_f32_16x16x32_bf16(                               \
                Aq[m4 * 2 + 1], BREG[n2 * 2 + 1], z0, 0, 0, 0);                    \
      }                                                                            \
    __builtin_amdgcn_s_setprio(0);

// epilogue slice of one FINALIZED quadrant: 16 packed 4B nt-stores (full 64B lines)
#define EPI_Q(qm, qn, CP, BBV) do {                                                \
    _Pragma("unroll")                                                              \
    for (int m4 = 0; m4 < 4; m4++)                                                 \
      _Pragma("unroll")                                                            \
      for (int j = 0; j < 4; j++) {                                                \
        int mm_ = (qm) * 4 + m4;                                                   \
        float v0_ = acc[mm_][(qn) * 2 + 0][j] + BBV[(qn) * 2 + 0];                 \
        float v1_ = acc[mm_][(qn) * 2 + 1][j] + BBV[(qn) * 2 + 1];                 \
        float g0_ = wgt * (0.5f * v0_ * (1.0f + erf_fast(v0_ * 0.70710678f)));     \
        float g1_ = wgt * (0.5f * v1_ * (1.0f + erf_fast(v1_ * 0.70710678f)));     \
        unsigned pk_ = (unsigned)f2bf(g0_) | ((unsigned)f2bf(g1_) << 16);          \
        __builtin_nontemporal_store(pk_,                                           \
            (unsigned*)((CP) + (mm_ * 16 + j) * 64 + (qn) * 32));                  \
      }                                                                            \
  } while (0)

#define PH_PRE                                                                     \
    __builtin_amdgcn_sched_barrier(0);                                             \
    __builtin_amdgcn_s_barrier();                                                  \
    asm volatile("s_waitcnt lgkmcnt(0)" ::: "memory");                             \
    __builtin_amdgcn_sched_barrier(0);

#define PH_POST(VM)                                                                \
    if ((VM) == 4) { asm volatile("s_waitcnt vmcnt(4)" ::: "memory"); }            \
    else if ((VM) == 1) { asm volatile("s_waitcnt vmcnt(0)" ::: "memory"); }       \
    else if ((VM) == 36) { asm volatile("s_waitcnt vmcnt(36)" ::: "memory"); }     \
    __builtin_amdgcn_sched_barrier(0);                                             \
    __builtin_amdgcn_s_barrier();

#define RD_A(buf, off)                                                             \
    _Pragma("unroll")                                                              \
    for (int m4 = 0; m4 < 4; m4++) {                                               \
      Aq[m4 * 2]     = *(const sh8*)(pA0 + (buf) * 32768 + (off) + m4 * 2048);     \
      Aq[m4 * 2 + 1] = *(const sh8*)(pA1 + (buf) * 32768 + (off) + m4 * 2048);     \
    }
#define RD_B(buf, off, BREG)                                                       \
    _Pragma("unroll")                                                              \
    for (int n2 = 0; n2 < 2; n2++) {                                               \
      BREG[n2 * 2]     = *(const sh8*)(pB0 + (buf) * 32768 + (off) + n2 * 2048);   \
      BREG[n2 * 2 + 1] = *(const sh8*)(pB1 + (buf) * 32768 + (off) + n2 * 2048);   \
    }

#define PH1(buf, STMT, VM) do { RD_A(buf, 0) RD_B(buf, 0, B0r)                     \
    STMT; PH_PRE MFMA_CL(0, 0, B0r) PH_POST(VM) } while (0)
#define PH2(buf, STMT, VM) do { RD_B(buf, 4096, B1r)                               \
    STMT; PH_PRE MFMA_CL(0, 1, B1r) PH_POST(VM) } while (0)
#define PH3(buf, STMT, VM) do { RD_A(buf, 8192)                                    \
    STMT; PH_PRE MFMA_CL(1, 1, B1r) PH_POST(VM) } while (0)
#define PH4(buf, STMT, VM) do {                                                    \
    STMT; PH_PRE MFMA_CL(1, 0, B0r) PH_POST(VM) } while (0)

#define PH1Z(buf, STMT, VM) do { RD_A(buf, 0) RD_B(buf, 0, B0r)                    \
    STMT; PH_PRE MFMA_CLZ(0, 0, B0r) PH_POST(VM) } while (0)
#define PH2Z(buf, STMT, VM) do { RD_B(buf, 4096, B1r)                              \
    STMT; PH_PRE MFMA_CLZ(0, 1, B1r) PH_POST(VM) } while (0)
#define PH3Z(buf, STMT, VM) do { RD_A(buf, 8192)                                   \
    STMT; PH_PRE MFMA_CLZ(1, 1, B1r) PH_POST(VM) } while (0)
#define PH4Z(buf, STMT, VM) do {                                                   \
    STMT; PH_PRE MFMA_CLZ(1, 0, B0r) PH_POST(VM) } while (0)

// stage unit = 2 gload_lds16 per thread (16KB).
#define STAGE_A(tau, q) do {                                                       \
    int bo_ = ((tau) & 1) * 32768;                                                 \
    if constexpr (MODE == 0) {                                                     \
      const unsigned short* ap_ = A0p + ((tau) & 15) * 64;                         \
      gload_lds16(ap_ + oA##q##0, lds + lA + bo_ + (q) * 8192);                    \
      gload_lds16(ap_ + oA##q##1, lds + lA + bo_ + (q) * 8192 + 16384);            \
    } else {                                                                       \
      int kt_ = ((tau) < NTH) ? (tau) : (tau) - NTH;                               \
      const unsigned short* ap_ = (((tau) < NTH) ? H0p : H1p) +                    \
                                  (kt_ >> 2) * 65536 + (kt_ & 3) * 16384;          \
      gload_lds16(ap_ + fA##q##0, lds + lA + bo_ + (q) * 8192);                    \
      gload_lds16(ap_ + fA##q##1, lds + lA + bo_ + (q) * 8192 + 16384);            \
    } } while (0)

#define STAGE_B(tau, q) do {                                                       \
    int bo_ = ((tau) & 1) * 32768;                                                 \
    if constexpr (MODE == 0) {                                                     \
      const unsigned short* bp_ = w1tE +                                           \
          (size_t)(nbh8 + ((tau) >> 4)) * (256 * HH) + ((tau) & 15) * 64;          \
      gload_lds16(bp_ + oB##q##0, lds + lB + bo_ + (q) * 4096);                    \
      gload_lds16(bp_ + oB##q##1, lds + lB + bo_ + (q) * 4096 + 16384);            \
    } else {                                                                       \
      int kt_ = ((tau) < NTH) ? (tau) : (tau) - NTH;                               \
      const unsigned short* bp_ = (((tau) < NTH) ? B0p : B1p) + kt_ * 64;          \
      gload_lds16(bp_ + oB##q##0, lds + lB + bo_ + (q) * 4096);                    \
      gload_lds16(bp_ + oB##q##1, lds + lB + bo_ + (q) * 4096 + 16384);            \
    } } while (0)

#define STD8(T)                                                                    \
    PH1(0, { STAGE_A((T) + 1, 1); }, 0);                                           \
    PH2(0, { STAGE_B((T) + 1, 1); }, 0);                                           \
    PH3(0, { STAGE_A((T) + 2, 0); }, 0);                                           \
    PH4(0, { STAGE_B((T) + 2, 0); }, 4);                                           \
    PH1(1, { STAGE_A((T) + 2, 1); }, 0);                                           \
    PH2(1, { STAGE_B((T) + 2, 1); }, 0);                                           \
    PH3(1, { STAGE_A((T) + 3, 0); }, 0);                                           \
    PH4(1, { STAGE_B((T) + 3, 0); }, 4);

// segment's LAST tile-pair: EPI slices of finalized quadrants in phases 6-8.
#define STD8E(T)                                                                   \
    PH1(0, { STAGE_A((T) + 1, 1); }, 0);                                           \
    PH2(0, { STAGE_B((T) + 1, 1); }, 0);                                           \
    PH3(0, { STAGE_A((T) + 2, 0); }, 0);                                           \
    PH4(0, { STAGE_B((T) + 2, 0); }, 4);                                           \
    PH1(1, { STAGE_A((T) + 2, 1); }, 0);                                           \
    PH2(1, { EPI_Q(0, 0, CpC, bbvC); STAGE_B((T) + 2, 1); }, 0);                   \
    PH3(1, { EPI_Q(0, 1, CpC, bbvC); STAGE_A((T) + 3, 0); }, 0);                   \
    PH4(1, { EPI_Q(1, 1, CpC, bbvC); STAGE_B((T) + 3, 0); }, 36);

// next segment's FIRST tile-pair: zero-C on tile T (buf0); EPI(1,0) of PREV segment
// in phase 1 (quadrant dead after; its zero-C re-creation is at phase 4).
#define STD8Z(T)                                                                   \
    PH1Z(0, { EPI_Q(1, 0, CpP, bbvP); STAGE_A((T) + 1, 1); }, 0);                  \
    PH2Z(0, { STAGE_B((T) + 1, 1); }, 0);                                          \
    PH3Z(0, { STAGE_A((T) + 2, 0); }, 0);                                          \
    PH4Z(0, { STAGE_B((T) + 2, 0); }, 4);                                          \
    PH1(1, { STAGE_A((T) + 2, 1); }, 0);                                           \
    PH2(1, { STAGE_B((T) + 2, 1); }, 0);                                           \
    PH3(1, { STAGE_A((T) + 3, 0); }, 0);                                           \
    PH4(1, { STAGE_B((T) + 3, 0); }, 4);

#define TAIL8(T)                                                                   \
    PH1(0, { STAGE_A((T) + 1, 1); }, 0);                                           \
    PH2(0, { STAGE_B((T) + 1, 1); }, 0);                                           \
    PH3(0, {}, 0);                                                                 \
    PH4(0, {}, 1);                                                                 \
    PH1(1, {}, 0);                                                                 \
    PH2(1, {}, 0);                                                                 \
    PH3(1, {}, 0);                                                                 \
    PH4(1, {}, 0);

// seg-7 tail: EPI slices in the empty phases 6-8; (1,0) serial after.
#define TAIL8E(T)                                                                  \
    PH1(0, { STAGE_A((T) + 1, 1); }, 0);                                           \
    PH2(0, { STAGE_B((T) + 1, 1); }, 0);                                           \
    PH3(0, {}, 0);                                                                 \
    PH4(0, {}, 1);                                                                 \
    PH1(1, {}, 0);                                                                 \
    PH2(1, { EPI_Q(0, 0, CpC, bbvC); }, 0);                                        \
    PH3(1, { EPI_Q(0, 1, CpC, bbvC); }, 0);                                        \
    PH4(1, { EPI_Q(1, 1, CpC, bbvC); }, 0);

template <int MODE>
__global__ __launch_bounds__(512, 1) void gemm8p(
    const unsigned short* __restrict__ XorH,   // MODE0: Xbf ; MODE1: hmid(v3)
    const unsigned short* __restrict__ Wt,     // MODE0: w1t ; MODE1: w2t(perm)
    const float* __restrict__ bias,            // MODE0: pb1 ; MODE1: pb2
    const int* __restrict__ re,
    const float* __restrict__ rw,
    unsigned short* __restrict__ hmid_out,     // MODE0 out (v3 layout)
    float* __restrict__ out) {                 // MODE1 out
  extern __shared__ char lds[];

  constexpr int NT  = 128;                         // total K-tiles (both modes)
  constexpr int NTH = (MODE == 0) ? NT : (FF / 64);// MODE1: expert switch at 64

  int P = blockIdx.x;
  int t = threadIdx.x;
  int lane = t & 63, wv = t >> 6;
  int wr = wv >> 2, wc = wv & 3;       // 2M x 4N waves
  int ln = lane & 15, kq = lane >> 4;

  const unsigned short *A0p = nullptr, *w1tE = nullptr;
  const unsigned short *H0p = nullptr, *H1p = nullptr, *B0p = nullptr, *B1p = nullptr;
  int pair = 0, b, e0 = 0, e1 = 0, mb, nb = 0, nbh8 = 0;
  int ldb;
  if constexpr (MODE == 0) {
    b = P & 7;                       // XCD <-> batch
    int k = P >> 3;                  // 0..31 per batch
    int pairbit = k & 1;
    mb = (k >> 1) & 7;
    nbh8 = (k >> 4) * 8;             // nb-half base (0 or 8)
    pair = b * 2 + pairbit;
    e0 = re[pair];
    A0p = XorH + (size_t)b * TT * HH + (size_t)mb * 256 * HH;  // fixed all segments
    w1tE = Wt + (size_t)e0 * FF * HH;
    ldb = HH;
  } else {
    b = P & 7;                       // XCD <-> batch
    int idx = P >> 3;
    nb = idx & 3; mb = idx >> 2;
    e0 = re[2 * b]; e1 = re[2 * b + 1];
    H0p = XorH + (size_t)(2 * b) * TT * FF + (size_t)mb * 16 * 65536;
    H1p = H0p + (size_t)TT * FF;
    B0p = Wt + (size_t)e0 * FF * HH + (size_t)nb * 256 * FF;
    B1p = Wt + (size_t)e1 * FF * HH + (size_t)nb * 256 * FF;
    ldb = FF;
  }

  // -------- precomputed per-lane addressing (loop-invariant) --------
  int lrow = t >> 3;                          // A stage row lane part (0..63)
  int lrB8 = (t >> 8) * 64 + ((t >> 3) & 31); // B stage row lane part
  int clel = ((t & 7) ^ ((t >> 3) & 7)) * 8;  // inverse-swizzled col (elements)
  // MODE0 A offsets (row-major Xbf, lda=HH)
  size_t oA00 = (size_t)(lrow)*HH + clel;
  size_t oA01 = (size_t)(128 + lrow) * HH + clel;
  size_t oA10 = (size_t)(64 + lrow) * HH + clel;
  size_t oA11 = (size_t)(192 + lrow) * HH + clel;
  // MODE1 A offsets (hmid v3: row*64 + col within [256][64] sub-tile) — contiguous.
  size_t fA00 = (size_t)(lrow)*64 + clel;
  size_t fA01 = (size_t)(128 + lrow) * 64 + clel;
  size_t fA10 = (size_t)(64 + lrow) * 64 + clel;
  size_t fA11 = (size_t)(192 + lrow) * 64 + clel;
  // B offsets (row-major Wt panels, ldb per mode)
  size_t oB00 = (size_t)(lrB8)*ldb + clel;
  size_t oB01 = (size_t)(128 + lrB8) * ldb + clel;
  size_t oB10 = (size_t)(32 + lrB8) * ldb + clel;
  size_t oB11 = (size_t)(160 + lrB8) * ldb + clel;
  // LDS stage dest lane bases (bytes)
  int lA = lrow * 128 + (t & 7) * 16;
  int lB = 65536 + lrB8 * 128 + (t & 7) * 16;
  // LDS read lane bases (bytes); row&7 == ln&7 for all fragment rows
  char* pA0 = lds + wr * 16384 + ln * 128 + ((kq ^ (ln & 7)) * 16);
  char* pA1 = lds + wr * 16384 + ln * 128 + (((4 + kq) ^ (ln & 7)) * 16);
  char* pB0 = lds + 65536 + wc * 8192 + ln * 128 + ((kq ^ (ln & 7)) * 16);
  char* pB1 = lds + 65536 + wc * 8192 + ln * 128 + (((4 + kq) ^ (ln & 7)) * 16);

  f32x4 acc[8][4];
#pragma unroll
  for (int m = 0; m < 8; m++)
#pragma unroll
    for (int n = 0; n < 4; n++) acc[m][n] = (f32x4){0.f, 0.f, 0.f, 0.f};

  sh8 Aq[8], B0r[4], B1r[4];

  // Prologue: tile0 fully (4 units), tile1 q0 (2 units). vmcnt(4)=2 units pending.
  STAGE_A(0, 0); STAGE_B(0, 0); STAGE_A(0, 1); STAGE_B(0, 1);
  STAGE_A(1, 0); STAGE_B(1, 0);
  asm volatile("s_waitcnt vmcnt(4)" ::: "memory");
  __builtin_amdgcn_sched_barrier(0);
  __builtin_amdgcn_s_barrier();

  if constexpr (MODE == 0) {
    float wgt = rw[pair];
    unsigned short* CpP = hmid_out;      // prev-seg store base (valid from seg 1)
    float bbvP[4] = {0.f, 0.f, 0.f, 0.f};
    for (int seg = 0; seg < 8; ++seg) {
      int nbs = nbh8 + seg;
      float bbvC[4];
#pragma unroll
      for (int nn = 0; nn < 4; nn++)
        bbvC[nn] = bias[(size_t)e0 * FF + nbs * 256 + wc * 64 + nn * 16 + ln];
      unsigned short* CpC = hmid_out + (size_t)pair * TT * FF +
                            (size_t)(mb * 16 + nbs) * 65536 + wc * 16384 +
                            (size_t)(wr * 128 + kq * 4) * 64 + ln * 2;
      int T0 = seg * 16;
      if (seg == 0) {
        STD8(T0);
      } else {
        STD8Z(T0);                       // zero-C + EPI(1,0) of seg-1 via CpP/bbvP
      }
      for (int it = 1; it < 7; ++it) {
        int T = T0 + it * 2;
        STD8(T);
      }
      if (seg < 7) {
        STD8E(T0 + 14);                  // EPI(0,0)/(0,1)/(1,1) sliced into ph 6-8
      } else {
        TAIL8E(126);
        EPI_Q(1, 0, CpC, bbvC);          // final quadrant, serial
      }
      CpP = CpC;
#pragma unroll
      for (int nn = 0; nn < 4; nn++) bbvP[nn] = bbvC[nn];
    }
  } else {
    for (int T = 0; T + 2 < NT; T += 2) {
      STD8(T);
    }
    TAIL8(NT - 2);
    // ----- epilogue: out = acc + weighted bias (nt stores, standard layout) -----
    float w0 = rw[2 * b], w1v = rw[2 * b + 1];
#pragma unroll
    for (int nn = 0; nn < 4; nn++) {
      int col = nb * 256 + wc * 64 + nn * 16 + ln;
      float bv = w0 * bias[(size_t)e0 * HH + col] + w1v * bias[(size_t)e1 * HH + col];
#pragma unroll
      for (int mm = 0; mm < 8; mm++) {
#pragma unroll
        for (int j = 0; j < 4; j++) {
          int row = mb * 256 + wr * 128 + mm * 16 + kq * 4 + j;
          __builtin_nontemporal_store(acc[mm][nn][j] + bv,
              &out[(size_t)b * TT * HH + (size_t)row * HH + col]);
        }
      }
    }
  }
}

extern "C" void kernel_launch(void* const* d_in, const int* in_sizes, int n_in,
                              void* d_out, int out_size, void* d_ws, size_t ws_size,
                              hipStream_t stream) {
  const float* X  = (const float*)d_in[0];
  const float* gw = (const float*)d_in[1];
  const float* w1 = (const float*)d_in[2];
  const float* pb1 = (const float*)d_in[3];
  const float* w2 = (const float*)d_in[4];
  const float* pb2 = (const float*)d_in[5];
  float* out = (float*)d_out;

  char* ws = (char*)d_ws;
  int* re = (int*)ws;                     // 16 ints
  float* rw = (float*)(ws + 64);          // 16 floats
  float* partial = (float*)(ws + 256);    // [B][16][H] f32 = 512KB
  unsigned short* Xbf = (unsigned short*)(ws + 256 + 524288);  // [B][T][H] bf16 = 32MB
  const size_t fixed = 256 + 524288 + (size_t)BB * TT * HH * 2;

  unsigned short* w1t = (unsigned short*)(ws + fixed);                          // 64MB
  unsigned short* w2t = (unsigned short*)(ws + fixed + (size_t)EE * HH * FF * 2);
  unsigned short* hmid = (unsigned short*)(ws + fixed + (size_t)2 * EE * HH * FF * 2); // 256MB

  hipFuncSetAttribute((const void*)gemm8p<0>,
                      hipFuncAttributeMaxDynamicSharedMemorySize, 131072);
  hipFuncSetAttribute((const void*)gemm8p<1>,
                      hipFuncAttributeMaxDynamicSharedMemorySize, 131072);

  prep<<<dim3(16, BB), 256, 0, stream>>>(X, Xbf, partial);
  gating_kernel<<<BB, 256, 0, stream>>>(partial, gw, re, rw);

  transposeE<<<dim3(HH / 64, FF / 64, EE), 256, 0, stream>>>(w1, w1t, re, HH, FF, 0);
  transposeE<<<dim3(FF / 64, HH / 64, EE), 256, 0, stream>>>(w2, w2t, re, FF, HH, 1);

  gemm8p<0><<<256, 512, 131072, stream>>>(Xbf, w1t, pb1, re, rw, hmid, nullptr);
  gemm8p<1><<<256, 512, 131072, stream>>>(hmid, w2t, pb2, re, rw, nullptr, out);
}

// Round 14
// 637.691 us; speedup vs baseline: 2.0804x; 2.0804x over previous
//
#include <hip/hip_runtime.h>
#include <hip/hip_bf16.h>
#include <math.h>

// Problem constants
#define BB 8
#define TT 2048
#define HH 1024
#define FF 4096
#define EE 8

typedef __attribute__((ext_vector_type(8))) short sh8;   // 8 bf16 (4 VGPRs)
typedef __attribute__((ext_vector_type(4))) short sh4;   // 4 bf16 (8B)
typedef __attribute__((ext_vector_type(4))) float f32x4; // MFMA acc
typedef __attribute__((ext_vector_type(4))) float f4;

__device__ inline unsigned short f2bf(float f) {
  unsigned u = __builtin_bit_cast(unsigned, f);
  u += 0x7FFFu + ((u >> 16) & 1u);
  return (unsigned short)(u >> 16);
}

// A&S 7.1.25 erf approximation, |err| <= 2.5e-5, branchless (3-term).
// Refchecked in R13 (absmax 0.0039, identical to 5-term).
__device__ inline float erf_fast(float x) {
  float ax = fabsf(x);
  float t = 1.0f / (1.0f + 0.47047f * ax);
  float y = t * (0.3480242f + t * (-0.0958798f + t * 0.7478556f));
  float e = __expf(-ax * ax);
  float r = 1.0f - y * e;
  return copysignf(r, x);
}

// async global->LDS, 16B per lane, wave-uniform LDS base + lane*16
__device__ inline void gload_lds16(const void* g, void* l) {
  __builtin_amdgcn_global_load_lds(
      (const __attribute__((address_space(1))) unsigned int*)g,
      (__attribute__((address_space(3))) unsigned int*)l, 16, 0, 0);
}

// ---------------- fused: X f32 -> bf16 AND per-chunk column partial sums ----------------
__global__ __launch_bounds__(256) void prep(const float* __restrict__ X,
                                            unsigned short* __restrict__ Xb,
                                            float* __restrict__ partial) {
  int tc = blockIdx.x, b = blockIdx.y, t = threadIdx.x;
  const float* src = X + ((size_t)b * TT + (size_t)tc * 128) * HH;
  unsigned short* dst = Xb + ((size_t)b * TT + (size_t)tc * 128) * HH;
  f4 s = {0.f, 0.f, 0.f, 0.f};
  for (int r = 0; r < 128; ++r) {
    f4 v = *(const f4*)&src[(size_t)r * HH + t * 4];
    s[0] += v[0]; s[1] += v[1]; s[2] += v[2]; s[3] += v[3];
    sh4 o;
    o[0] = (short)f2bf(v[0]); o[1] = (short)f2bf(v[1]);
    o[2] = (short)f2bf(v[2]); o[3] = (short)f2bf(v[3]);
    *(sh4*)&dst[(size_t)r * HH + t * 4] = o;
  }
  *(f4*)&partial[((size_t)b * 16 + tc) * HH + t * 4] = s;
}

// ---------------- gating: logits -> softmax -> top2 -> routing ----------------
__global__ __launch_bounds__(256) void gating_kernel(const float* __restrict__ partial,
                                                     const float* __restrict__ gw,
                                                     int* __restrict__ re,
                                                     float* __restrict__ rw) {
  int b = blockIdx.x, t = threadIdx.x;
  float acc[EE];
#pragma unroll
  for (int e = 0; e < EE; e++) acc[e] = 0.f;
  for (int jj = 0; jj < 4; jj++) {
    int h = t + jj * 256;
    float s = 0.f;
    for (int tc = 0; tc < 16; tc++) s += partial[((size_t)b * 16 + tc) * HH + h];
    s *= (1.0f / (float)TT);
#pragma unroll
    for (int e = 0; e < EE; e++) acc[e] += s * gw[h * EE + e];
  }
#pragma unroll
  for (int off = 32; off >= 1; off >>= 1) {
#pragma unroll
    for (int e = 0; e < EE; e++) acc[e] += __shfl_down(acc[e], off);
  }
  __shared__ float red[4][EE];
  if ((t & 63) == 0) {
#pragma unroll
    for (int e = 0; e < EE; e++) red[t >> 6][e] = acc[e];
  }
  __syncthreads();
  if (t == 0) {
    float lg[EE];
#pragma unroll
    for (int e = 0; e < EE; e++) lg[e] = red[0][e] + red[1][e] + red[2][e] + red[3][e];
    float mx = lg[0];
#pragma unroll
    for (int e = 1; e < EE; e++) mx = fmaxf(mx, lg[e]);
    float p[EE]; float s = 0.f;
#pragma unroll
    for (int e = 0; e < EE; e++) { p[e] = expf(lg[e] - mx); s += p[e]; }
#pragma unroll
    for (int e = 0; e < EE; e++) p[e] /= s;
    int i1 = 0;
#pragma unroll
    for (int e = 1; e < EE; e++) if (p[e] > p[i1]) i1 = e;  // first index wins ties
    int i2 = -1;
#pragma unroll
    for (int e = 0; e < EE; e++) {
      if (e == i1) continue;
      if (i2 < 0 || p[e] > p[i2]) i2 = e;
    }
    float den = p[i1] + p[i2];
    re[b * 2 + 0] = i1; rw[b * 2 + 0] = p[i1] / den;
    re[b * 2 + 1] = i2; rw[b * 2 + 1] = p[i2] / den;
  }
}

// ---------------- transpose+convert per-EXPERT weights: W[e][K][N] f32 -> Wt[e][N][K] bf16
// perm=1 (w2): within each K-32 block, stored position c holds logical
// k = (c&32) + (c&1)*16 + ((c>>1)&15) — matching hmid v3's f-permutation so the
// MFMA K-order is consistent between A (hmid) and B (w2t) in MODE1.
__global__ __launch_bounds__(256) void transposeE(const float* __restrict__ W,
                                                  unsigned short* __restrict__ Wt,
                                                  const int* __restrict__ re,
                                                  int K, int N, int perm) {
  int e = blockIdx.z;
  bool u = false;
#pragma unroll
  for (int p = 0; p < 16; p++) u = u || (re[p] == e);
  if (!u) return;

  __shared__ float tile[64][65];
  int kb = blockIdx.x, nb = blockIdx.y;
  const float* src = W + (size_t)e * K * N + (size_t)(kb * 64) * N + nb * 64;
  int t = threadIdx.x;
#pragma unroll
  for (int pass = 0; pass < 4; pass++) {
    int r = (t >> 4) + pass * 16;
    int c = (t & 15) * 4;
    *(f4*)&tile[r][c] = *(const f4*)&src[(size_t)r * N + c];
  }
  __syncthreads();
#pragma unroll
  for (int pass = 0; pass < 2; pass++) {
    int idx = (t + pass * 256) * 8;
    int nl = idx >> 6, k0 = idx & 63;
    sh8 o;
    if (perm) {
#pragma unroll
      for (int j = 0; j < 8; j++) {
        int local = (k0 & 31) + j;
        int kk = (k0 & 32) + ((local & 1) << 4) + (local >> 1);
        o[j] = (short)f2bf(tile[kk][nl]);
      }
    } else {
#pragma unroll
      for (int j = 0; j < 8; j++) o[j] = (short)f2bf(tile[k0 + j][nl]);
    }
    *(sh8*)&Wt[(size_t)e * N * K + (size_t)(nb * 64 + nl) * K + kb * 64 + k0] = o;
  }
}

// ================= 256x256 8-phase counted-vmcnt GEMM (T1+T2+T3+T4+T5) =================
// R14 = R12 structure EXACTLY (persistent MODE0, SERIAL per-segment epilogue; the
// three epilogue-hiding attempts R9/R10/R13 all regressed via scratch spill — nothing
// consuming acc or storing may live inside the counted-vmcnt K-loop) with two
// epilogue-local changes:
//   (1) MODE0 epilogue stores are PLAIN (not nontemporal): each segment's 32MB/XCD
//       store burst lands in the local L2 (4MB/XCD = exactly the burst) and writes
//       back lazily under the next segment's K-loop, instead of a synchronized
//       HBM-ceiling burst while the pipeline is stopped.
//   (2) 3-term erf (R13-refchecked) halves the epilogue VALU.
// hmid v3 (elements, per pair): (mb*16+f256)*65536 + wc*16384 + row*64 + c, where
//   logical f = nn*16+ln stored at c = (nn>>1)*32 + ln*2 + (nn&1); w2t carries the
//   identical K-permutation (transposeE perm=1). MODE1 stage reads are 1KB contiguous.
// MODE 0 (PERSISTENT): grid 256, block = (pair, mb, nbhalf); 8 nb-segments with a
//   continuous K-pipeline; per-segment serial epilogue; acc re-zeroed per segment.
// MODE 1: out[b] = hmid-pair-concat (K) @ w2t^T + weighted b2.
// LDS 128KB: A[2][256][64] + B[2][256][64] bf16, XOR swizzle byte ^= (row&7)<<4 via
//   inverse-swizzled GLOBAL SOURCE + swizzled ds_read. Frags read ONCE per tile (24).
// vmcnt ledger: prologue 12 issued, vmcnt(4); steady vmcnt(4) at phases 4/8; final
//   tail stages only tile NT-1 q1 and uses vmcnt(0) at phase 4.

#define MFMA_CL(qm, qn, BREG)                                                      \
    __builtin_amdgcn_s_setprio(1);                                                 \
    _Pragma("unroll")                                                              \
    for (int m4 = 0; m4 < 4; m4++)                                                 \
      _Pragma("unroll")                                                            \
      for (int n2 = 0; n2 < 2; n2++)                                               \
        _Pragma("unroll")                                                          \
        for (int kk = 0; kk < 2; kk++)                                             \
          acc[(qm) * 4 + m4][(qn) * 2 + n2] =                                      \
              __builtin_amdgcn_mfma_f32_16x16x32_bf16(                             \
                  Aq[m4 * 2 + kk], BREG[n2 * 2 + kk],                              \
                  acc[(qm) * 4 + m4][(qn) * 2 + n2], 0, 0, 0);                     \
    __builtin_amdgcn_s_setprio(0);

#define PH_PRE                                                                     \
    __builtin_amdgcn_sched_barrier(0);                                             \
    __builtin_amdgcn_s_barrier();                                                  \
    asm volatile("s_waitcnt lgkmcnt(0)" ::: "memory");                             \
    __builtin_amdgcn_sched_barrier(0);

#define PH_POST(VM)                                                                \
    if ((VM) == 4) { asm volatile("s_waitcnt vmcnt(4)" ::: "memory"); }            \
    else if ((VM) == 1) { asm volatile("s_waitcnt vmcnt(0)" ::: "memory"); }       \
    __builtin_amdgcn_sched_barrier(0);                                             \
    __builtin_amdgcn_s_barrier();

#define RD_A(buf, off)                                                             \
    _Pragma("unroll")                                                              \
    for (int m4 = 0; m4 < 4; m4++) {                                               \
      Aq[m4 * 2]     = *(const sh8*)(pA0 + (buf) * 32768 + (off) + m4 * 2048);     \
      Aq[m4 * 2 + 1] = *(const sh8*)(pA1 + (buf) * 32768 + (off) + m4 * 2048);     \
    }
#define RD_B(buf, off, BREG)                                                       \
    _Pragma("unroll")                                                              \
    for (int n2 = 0; n2 < 2; n2++) {                                               \
      BREG[n2 * 2]     = *(const sh8*)(pB0 + (buf) * 32768 + (off) + n2 * 2048);   \
      BREG[n2 * 2 + 1] = *(const sh8*)(pB1 + (buf) * 32768 + (off) + n2 * 2048);   \
    }

#define PH1(buf, STMT, VM) do { RD_A(buf, 0) RD_B(buf, 0, B0r)                     \
    STMT; PH_PRE MFMA_CL(0, 0, B0r) PH_POST(VM) } while (0)
#define PH2(buf, STMT, VM) do { RD_B(buf, 4096, B1r)                               \
    STMT; PH_PRE MFMA_CL(0, 1, B1r) PH_POST(VM) } while (0)
#define PH3(buf, STMT, VM) do { RD_A(buf, 8192)                                    \
    STMT; PH_PRE MFMA_CL(1, 1, B1r) PH_POST(VM) } while (0)
#define PH4(buf, STMT, VM) do {                                                    \
    STMT; PH_PRE MFMA_CL(1, 0, B0r) PH_POST(VM) } while (0)

// stage unit = 2 gload_lds16 per thread (16KB).
#define STAGE_A(tau, q) do {                                                       \
    int bo_ = ((tau) & 1) * 32768;                                                 \
    if constexpr (MODE == 0) {                                                     \
      const unsigned short* ap_ = A0p + ((tau) & 15) * 64;                         \
      gload_lds16(ap_ + oA##q##0, lds + lA + bo_ + (q) * 8192);                    \
      gload_lds16(ap_ + oA##q##1, lds + lA + bo_ + (q) * 8192 + 16384);            \
    } else {                                                                       \
      int kt_ = ((tau) < NTH) ? (tau) : (tau) - NTH;                               \
      const unsigned short* ap_ = (((tau) < NTH) ? H0p : H1p) +                    \
                                  (kt_ >> 2) * 65536 + (kt_ & 3) * 16384;          \
      gload_lds16(ap_ + fA##q##0, lds + lA + bo_ + (q) * 8192);                    \
      gload_lds16(ap_ + fA##q##1, lds + lA + bo_ + (q) * 8192 + 16384);            \
    } } while (0)

#define STAGE_B(tau, q) do {                                                       \
    int bo_ = ((tau) & 1) * 32768;                                                 \
    if constexpr (MODE == 0) {                                                     \
      const unsigned short* bp_ = w1tE +                                           \
          (size_t)(nbh8 + ((tau) >> 4)) * (256 * HH) + ((tau) & 15) * 64;          \
      gload_lds16(bp_ + oB##q##0, lds + lB + bo_ + (q) * 4096);                    \
      gload_lds16(bp_ + oB##q##1, lds + lB + bo_ + (q) * 4096 + 16384);            \
    } else {                                                                       \
      int kt_ = ((tau) < NTH) ? (tau) : (tau) - NTH;                               \
      const unsigned short* bp_ = (((tau) < NTH) ? B0p : B1p) + kt_ * 64;          \
      gload_lds16(bp_ + oB##q##0, lds + lB + bo_ + (q) * 4096);                    \
      gload_lds16(bp_ + oB##q##1, lds + lB + bo_ + (q) * 4096 + 16384);            \
    } } while (0)

#define STD8(T)                                                                    \
    PH1(0, { STAGE_A((T) + 1, 1); }, 0);                                           \
    PH2(0, { STAGE_B((T) + 1, 1); }, 0);                                           \
    PH3(0, { STAGE_A((T) + 2, 0); }, 0);                                           \
    PH4(0, { STAGE_B((T) + 2, 0); }, 4);                                           \
    PH1(1, { STAGE_A((T) + 2, 1); }, 0);                                           \
    PH2(1, { STAGE_B((T) + 2, 1); }, 0);                                           \
    PH3(1, { STAGE_A((T) + 3, 0); }, 0);                                           \
    PH4(1, { STAGE_B((T) + 3, 0); }, 4);

#define TAIL8(T)                                                                   \
    PH1(0, { STAGE_A((T) + 1, 1); }, 0);                                           \
    PH2(0, { STAGE_B((T) + 1, 1); }, 0);                                           \
    PH3(0, {}, 0);                                                                 \
    PH4(0, {}, 1);                                                                 \
    PH1(1, {}, 0);                                                                 \
    PH2(1, {}, 0);                                                                 \
    PH3(1, {}, 0);                                                                 \
    PH4(1, {}, 0);

template <int MODE>
__global__ __launch_bounds__(512, 1) void gemm8p(
    const unsigned short* __restrict__ XorH,   // MODE0: Xbf ; MODE1: hmid(v3)
    const unsigned short* __restrict__ Wt,     // MODE0: w1t ; MODE1: w2t(perm)
    const float* __restrict__ bias,            // MODE0: pb1 ; MODE1: pb2
    const int* __restrict__ re,
    const float* __restrict__ rw,
    unsigned short* __restrict__ hmid_out,     // MODE0 out (v3 layout)
    float* __restrict__ out) {                 // MODE1 out
  extern __shared__ char lds[];

  constexpr int NT  = 128;                         // total K-tiles (both modes)
  constexpr int NTH = (MODE == 0) ? NT : (FF / 64);// MODE1: expert switch at 64

  int P = blockIdx.x;
  int t = threadIdx.x;
  int lane = t & 63, wv = t >> 6;
  int wr = wv >> 2, wc = wv & 3;       // 2M x 4N waves
  int ln = lane & 15, kq = lane >> 4;

  const unsigned short *A0p = nullptr, *w1tE = nullptr;
  const unsigned short *H0p = nullptr, *H1p = nullptr, *B0p = nullptr, *B1p = nullptr;
  int pair = 0, b, e0 = 0, e1 = 0, mb, nb = 0, nbh8 = 0;
  int ldb;
  if constexpr (MODE == 0) {
    b = P & 7;                       // XCD <-> batch
    int k = P >> 3;                  // 0..31 per batch
    int pairbit = k & 1;
    mb = (k >> 1) & 7;
    nbh8 = (k >> 4) * 8;             // nb-half base (0 or 8)
    pair = b * 2 + pairbit;
    e0 = re[pair];
    A0p = XorH + (size_t)b * TT * HH + (size_t)mb * 256 * HH;  // fixed all segments
    w1tE = Wt + (size_t)e0 * FF * HH;
    ldb = HH;
  } else {
    b = P & 7;                       // XCD <-> batch
    int idx = P >> 3;
    nb = idx & 3; mb = idx >> 2;
    e0 = re[2 * b]; e1 = re[2 * b + 1];
    H0p = XorH + (size_t)(2 * b) * TT * FF + (size_t)mb * 16 * 65536;
    H1p = H0p + (size_t)TT * FF;
    B0p = Wt + (size_t)e0 * FF * HH + (size_t)nb * 256 * FF;
    B1p = Wt + (size_t)e1 * FF * HH + (size_t)nb * 256 * FF;
    ldb = FF;
  }

  // -------- precomputed per-lane addressing (loop-invariant) --------
  int lrow = t >> 3;                          // A stage row lane part (0..63)
  int lrB8 = (t >> 8) * 64 + ((t >> 3) & 31); // B stage row lane part
  int clel = ((t & 7) ^ ((t >> 3) & 7)) * 8;  // inverse-swizzled col (elements)
  // MODE0 A offsets (row-major Xbf, lda=HH)
  size_t oA00 = (size_t)(lrow)*HH + clel;
  size_t oA01 = (size_t)(128 + lrow) * HH + clel;
  size_t oA10 = (size_t)(64 + lrow) * HH + clel;
  size_t oA11 = (size_t)(192 + lrow) * HH + clel;
  // MODE1 A offsets (hmid v3: row*64 + col within [256][64] sub-tile) — contiguous.
  size_t fA00 = (size_t)(lrow)*64 + clel;
  size_t fA01 = (size_t)(128 + lrow) * 64 + clel;
  size_t fA10 = (size_t)(64 + lrow) * 64 + clel;
  size_t fA11 = (size_t)(192 + lrow) * 64 + clel;
  // B offsets (row-major Wt panels, ldb per mode)
  size_t oB00 = (size_t)(lrB8)*ldb + clel;
  size_t oB01 = (size_t)(128 + lrB8) * ldb + clel;
  size_t oB10 = (size_t)(32 + lrB8) * ldb + clel;
  size_t oB11 = (size_t)(160 + lrB8) * ldb + clel;
  // LDS stage dest lane bases (bytes)
  int lA = lrow * 128 + (t & 7) * 16;
  int lB = 65536 + lrB8 * 128 + (t & 7) * 16;
  // LDS read lane bases (bytes); row&7 == ln&7 for all fragment rows
  char* pA0 = lds + wr * 16384 + ln * 128 + ((kq ^ (ln & 7)) * 16);
  char* pA1 = lds + wr * 16384 + ln * 128 + (((4 + kq) ^ (ln & 7)) * 16);
  char* pB0 = lds + 65536 + wc * 8192 + ln * 128 + ((kq ^ (ln & 7)) * 16);
  char* pB1 = lds + 65536 + wc * 8192 + ln * 128 + (((4 + kq) ^ (ln & 7)) * 16);

  f32x4 acc[8][4];
#pragma unroll
  for (int m = 0; m < 8; m++)
#pragma unroll
    for (int n = 0; n < 4; n++) acc[m][n] = (f32x4){0.f, 0.f, 0.f, 0.f};

  sh8 Aq[8], B0r[4], B1r[4];

  // Prologue: tile0 fully (4 units), tile1 q0 (2 units). vmcnt(4)=2 units pending.
  STAGE_A(0, 0); STAGE_B(0, 0); STAGE_A(0, 1); STAGE_B(0, 1);
  STAGE_A(1, 0); STAGE_B(1, 0);
  asm volatile("s_waitcnt vmcnt(4)" ::: "memory");
  __builtin_amdgcn_sched_barrier(0);
  __builtin_amdgcn_s_barrier();

  if constexpr (MODE == 0) {
    float wgt = rw[pair];
    for (int seg = 0; seg < 8; ++seg) {
      int nIt = (seg == 7) ? 7 : 8;
      for (int it = 0; it < nIt; ++it) {
        int T = seg * 16 + it * 2;
        STD8(T);
      }
      if (seg == 7) { TAIL8(126); }
      // ----- segment epilogue: v3 packed 4B PLAIN stores (absorbed by local L2,
      //       written back lazily under the next segment's K-loop) -----
      {
        int nbs = nbh8 + seg;
        float bbv[4];
#pragma unroll
        for (int nn = 0; nn < 4; nn++)
          bbv[nn] = bias[(size_t)e0 * FF + nbs * 256 + wc * 64 + nn * 16 + ln];
        // v3: logical f=nn*16+ln stored at c = (nn>>1)*32 + ln*2 + (nn&1).
        unsigned short* Cp = hmid_out + (size_t)pair * TT * FF +
                             (size_t)(mb * 16 + nbs) * 65536 + wc * 16384 +
                             (size_t)(wr * 128 + kq * 4) * 64 + ln * 2;
#pragma unroll
        for (int mm = 0; mm < 8; mm++) {
#pragma unroll
          for (int j = 0; j < 4; j++) {
            float gv[4];
#pragma unroll
            for (int nn = 0; nn < 4; nn++) {
              float v = acc[mm][nn][j] + bbv[nn];
              gv[nn] = wgt * (0.5f * v * (1.0f + erf_fast(v * 0.70710678118654752f)));
            }
            unsigned pk0 = (unsigned)f2bf(gv[0]) | ((unsigned)f2bf(gv[1]) << 16);
            unsigned pk1 = (unsigned)f2bf(gv[2]) | ((unsigned)f2bf(gv[3]) << 16);
            *(unsigned*)(Cp + (mm * 16 + j) * 64) = pk0;
            *(unsigned*)(Cp + (mm * 16 + j) * 64 + 32) = pk1;
          }
        }
#pragma unroll
        for (int m = 0; m < 8; m++)
#pragma unroll
          for (int n = 0; n < 4; n++) acc[m][n] = (f32x4){0.f, 0.f, 0.f, 0.f};
      }
    }
  } else {
    for (int T = 0; T + 2 < NT; T += 2) {
      STD8(T);
    }
    TAIL8(NT - 2);
    // ----- epilogue: out = acc + weighted bias (nt stores, standard layout) -----
    float w0 = rw[2 * b], w1v = rw[2 * b + 1];
#pragma unroll
    for (int nn = 0; nn < 4; nn++) {
      int col = nb * 256 + wc * 64 + nn * 16 + ln;
      float bv = w0 * bias[(size_t)e0 * HH + col] + w1v * bias[(size_t)e1 * HH + col];
#pragma unroll
      for (int mm = 0; mm < 8; mm++) {
#pragma unroll
        for (int j = 0; j < 4; j++) {
          int row = mb * 256 + wr * 128 + mm * 16 + kq * 4 + j;
          __builtin_nontemporal_store(acc[mm][nn][j] + bv,
              &out[(size_t)b * TT * HH + (size_t)row * HH + col]);
        }
      }
    }
  }
}

extern "C" void kernel_launch(void* const* d_in, const int* in_sizes, int n_in,
                              void* d_out, int out_size, void* d_ws, size_t ws_size,
                              hipStream_t stream) {
  const float* X  = (const float*)d_in[0];
  const float* gw = (const float*)d_in[1];
  const float* w1 = (const float*)d_in[2];
  const float* pb1 = (const float*)d_in[3];
  const float* w2 = (const float*)d_in[4];
  const float* pb2 = (const float*)d_in[5];
  float* out = (float*)d_out;

  char* ws = (char*)d_ws;
  int* re = (int*)ws;                     // 16 ints
  float* rw = (float*)(ws + 64);          // 16 floats
  float* partial = (float*)(ws + 256);    // [B][16][H] f32 = 512KB
  unsigned short* Xbf = (unsigned short*)(ws + 256 + 524288);  // [B][T][H] bf16 = 32MB
  const size_t fixed = 256 + 524288 + (size_t)BB * TT * HH * 2;

  unsigned short* w1t = (unsigned short*)(ws + fixed);                          // 64MB
  unsigned short* w2t = (unsigned short*)(ws + fixed + (size_t)EE * HH * FF * 2);
  unsigned short* hmid = (unsigned short*)(ws + fixed + (size_t)2 * EE * HH * FF * 2); // 256MB

  hipFuncSetAttribute((const void*)gemm8p<0>,
                      hipFuncAttributeMaxDynamicSharedMemorySize, 131072);
  hipFuncSetAttribute((const void*)gemm8p<1>,
                      hipFuncAttributeMaxDynamicSharedMemorySize, 131072);

  prep<<<dim3(16, BB), 256, 0, stream>>>(X, Xbf, partial);
  gating_kernel<<<BB, 256, 0, stream>>>(partial, gw, re, rw);

  transposeE<<<dim3(HH / 64, FF / 64, EE), 256, 0, stream>>>(w1, w1t, re, HH, FF, 0);
  transposeE<<<dim3(FF / 64, HH / 64, EE), 256, 0, stream>>>(w2, w2t, re, FF, HH, 1);

  gemm8p<0><<<256, 512, 131072, stream>>>(Xbf, w1t, pb1, re, rw, hmid, nullptr);
  gemm8p<1><<<256, 512, 131072, stream>>>(hmid, w2t, pb2, re, rw, nullptr, out);
}

// Round 15
// 627.304 us; speedup vs baseline: 2.1149x; 1.0166x over previous
//
#include <hip/hip_runtime.h>
#include <hip/hip_bf16.h>
#include <math.h>

// Problem constants
#define BB 8
#define TT 2048
#define HH 1024
#define FF 4096
#define EE 8

typedef __attribute__((ext_vector_type(8))) short sh8;   // 8 bf16 (4 VGPRs)
typedef __attribute__((ext_vector_type(4))) short sh4;   // 4 bf16 (8B)
typedef __attribute__((ext_vector_type(4))) float f32x4; // MFMA acc
typedef __attribute__((ext_vector_type(4))) float f4;

__device__ inline unsigned short f2bf(float f) {
  unsigned u = __builtin_bit_cast(unsigned, f);
  u += 0x7FFFu + ((u >> 16) & 1u);
  return (unsigned short)(u >> 16);
}

// A&S 7.1.25 erf approximation, |err| <= 2.5e-5, branchless (3-term).
// Refchecked R13/R14 (absmax 0.0039, identical to 5-term).
__device__ inline float erf_fast(float x) {
  float ax = fabsf(x);
  float t = 1.0f / (1.0f + 0.47047f * ax);
  float y = t * (0.3480242f + t * (-0.0958798f + t * 0.7478556f));
  float e = __expf(-ax * ax);
  float r = 1.0f - y * e;
  return copysignf(r, x);
}

// async global->LDS, 16B per lane, wave-uniform LDS base + lane*16
__device__ inline void gload_lds16(const void* g, void* l) {
  __builtin_amdgcn_global_load_lds(
      (const __attribute__((address_space(1))) unsigned int*)g,
      (__attribute__((address_space(3))) unsigned int*)l, 16, 0, 0);
}

// ---------------- fused: X f32 -> bf16 AND per-chunk column partial sums ----------------
__global__ __launch_bounds__(256) void prep(const float* __restrict__ X,
                                            unsigned short* __restrict__ Xb,
                                            float* __restrict__ partial) {
  int tc = blockIdx.x, b = blockIdx.y, t = threadIdx.x;
  const float* src = X + ((size_t)b * TT + (size_t)tc * 128) * HH;
  unsigned short* dst = Xb + ((size_t)b * TT + (size_t)tc * 128) * HH;
  f4 s = {0.f, 0.f, 0.f, 0.f};
  for (int r = 0; r < 128; ++r) {
    f4 v = *(const f4*)&src[(size_t)r * HH + t * 4];
    s[0] += v[0]; s[1] += v[1]; s[2] += v[2]; s[3] += v[3];
    sh4 o;
    o[0] = (short)f2bf(v[0]); o[1] = (short)f2bf(v[1]);
    o[2] = (short)f2bf(v[2]); o[3] = (short)f2bf(v[3]);
    *(sh4*)&dst[(size_t)r * HH + t * 4] = o;
  }
  *(f4*)&partial[((size_t)b * 16 + tc) * HH + t * 4] = s;
}

// ---------------- gating: logits -> softmax -> top2 -> routing ----------------
__global__ __launch_bounds__(256) void gating_kernel(const float* __restrict__ partial,
                                                     const float* __restrict__ gw,
                                                     int* __restrict__ re,
                                                     float* __restrict__ rw) {
  int b = blockIdx.x, t = threadIdx.x;
  float acc[EE];
#pragma unroll
  for (int e = 0; e < EE; e++) acc[e] = 0.f;
  for (int jj = 0; jj < 4; jj++) {
    int h = t + jj * 256;
    float s = 0.f;
    for (int tc = 0; tc < 16; tc++) s += partial[((size_t)b * 16 + tc) * HH + h];
    s *= (1.0f / (float)TT);
#pragma unroll
    for (int e = 0; e < EE; e++) acc[e] += s * gw[h * EE + e];
  }
#pragma unroll
  for (int off = 32; off >= 1; off >>= 1) {
#pragma unroll
    for (int e = 0; e < EE; e++) acc[e] += __shfl_down(acc[e], off);
  }
  __shared__ float red[4][EE];
  if ((t & 63) == 0) {
#pragma unroll
    for (int e = 0; e < EE; e++) red[t >> 6][e] = acc[e];
  }
  __syncthreads();
  if (t == 0) {
    float lg[EE];
#pragma unroll
    for (int e = 0; e < EE; e++) lg[e] = red[0][e] + red[1][e] + red[2][e] + red[3][e];
    float mx = lg[0];
#pragma unroll
    for (int e = 1; e < EE; e++) mx = fmaxf(mx, lg[e]);
    float p[EE]; float s = 0.f;
#pragma unroll
    for (int e = 0; e < EE; e++) { p[e] = expf(lg[e] - mx); s += p[e]; }
#pragma unroll
    for (int e = 0; e < EE; e++) p[e] /= s;
    int i1 = 0;
#pragma unroll
    for (int e = 1; e < EE; e++) if (p[e] > p[i1]) i1 = e;  // first index wins ties
    int i2 = -1;
#pragma unroll
    for (int e = 0; e < EE; e++) {
      if (e == i1) continue;
      if (i2 < 0 || p[e] > p[i2]) i2 = e;
    }
    float den = p[i1] + p[i2];
    re[b * 2 + 0] = i1; rw[b * 2 + 0] = p[i1] / den;
    re[b * 2 + 1] = i2; rw[b * 2 + 1] = p[i2] / den;
  }
}

// ---------------- transpose+convert per-EXPERT weights: W[e][K][N] f32 -> Wt[e][N][K] bf16
// perm=1 (w2): within each K-32 block, stored position c holds logical
// k = (c&32) + (c&1)*16 + ((c>>1)&15) — matching hmid v3's f-permutation so the
// MFMA K-order is consistent between A (hmid) and B (w2t) in MODE1.
__global__ __launch_bounds__(256) void transposeE(const float* __restrict__ W,
                                                  unsigned short* __restrict__ Wt,
                                                  const int* __restrict__ re,
                                                  int K, int N, int perm) {
  int e = blockIdx.z;
  bool u = false;
#pragma unroll
  for (int p = 0; p < 16; p++) u = u || (re[p] == e);
  if (!u) return;

  __shared__ float tile[64][65];
  int kb = blockIdx.x, nb = blockIdx.y;
  const float* src = W + (size_t)e * K * N + (size_t)(kb * 64) * N + nb * 64;
  int t = threadIdx.x;
#pragma unroll
  for (int pass = 0; pass < 4; pass++) {
    int r = (t >> 4) + pass * 16;
    int c = (t & 15) * 4;
    *(f4*)&tile[r][c] = *(const f4*)&src[(size_t)r * N + c];
  }
  __syncthreads();
#pragma unroll
  for (int pass = 0; pass < 2; pass++) {
    int idx = (t + pass * 256) * 8;
    int nl = idx >> 6, k0 = idx & 63;
    sh8 o;
    if (perm) {
#pragma unroll
      for (int j = 0; j < 8; j++) {
        int local = (k0 & 31) + j;
        int kk = (k0 & 32) + ((local & 1) << 4) + (local >> 1);
        o[j] = (short)f2bf(tile[kk][nl]);
      }
    } else {
#pragma unroll
      for (int j = 0; j < 8; j++) o[j] = (short)f2bf(tile[k0 + j][nl]);
    }
    *(sh8*)&Wt[(size_t)e * N * K + (size_t)(nb * 64 + nl) * K + kb * 64 + k0] = o;
  }
}

// ================= 256x256 8-phase counted-vmcnt GEMM (T1+T2+T3+T4+T5) =================
// R15 = R14 with ONE change: the PH_POST s_barrier is kept ONLY at vmcnt phases
// (4/8 and tail), dropped at VM==0 phases (6 of 16 barriers per tile-pair removed).
// Safety derivation: a STAGE write to buffer rows at phase p is ordered against all
// other waves' reads of those rows because (a) every reader's ds_read completes
// before its own lgkmcnt(0), which precedes that reader's NEXT PH_PRE barrier, and
// (b) the writer issues its gload_lds only after passing that same PH_PRE barrier.
// Cross-wave load-drain visibility (reads of freshly staged buffers) begins only at
// phases 5/1, protected by the KEPT barriers at phases 4/8 (per-wave vmcnt + bar).
// All 8 phase-top RD data dependencies verified covered by a kept-barrier phase.
// sched_barrier(0) retained everywhere (codegen pinning). Waves may now drift within
// a phase-group -> T5-style role-split (MFMA of fast waves overlaps VALU of slow).
// hmid v3 (elements, per pair): (mb*16+f256)*65536 + wc*16384 + row*64 + c, where
//   logical f = nn*16+ln stored at c = (nn>>1)*32 + ln*2 + (nn&1); w2t carries the
//   identical K-permutation (transposeE perm=1). MODE1 stage reads 1KB contiguous.
// MODE 0 (PERSISTENT): grid 256, block = (pair, mb, nbhalf); 8 nb-segments with a
//   continuous K-pipeline; per-segment serial epilogue (plain packed 4B stores);
//   acc re-zeroed per segment. [Epilogue-hiding attempts R9/R10/R13 all regressed
//   via scratch spill — nothing consuming acc or storing may live in the K-loop.]
// MODE 1: out[b] = hmid-pair-concat (K) @ w2t^T + weighted b2.
// LDS 128KB: A[2][256][64] + B[2][256][64] bf16, XOR swizzle byte ^= (row&7)<<4 via
//   inverse-swizzled GLOBAL SOURCE + swizzled ds_read. Frags read ONCE per tile (24).
// vmcnt ledger: prologue 12 issued, vmcnt(4); steady vmcnt(4) at phases 4/8; final
//   tail stages only tile NT-1 q1 and uses vmcnt(0) at phase 4.

#define MFMA_CL(qm, qn, BREG)                                                      \
    __builtin_amdgcn_s_setprio(1);                                                 \
    _Pragma("unroll")                                                              \
    for (int m4 = 0; m4 < 4; m4++)                                                 \
      _Pragma("unroll")                                                            \
      for (int n2 = 0; n2 < 2; n2++)                                               \
        _Pragma("unroll")                                                          \
        for (int kk = 0; kk < 2; kk++)                                             \
          acc[(qm) * 4 + m4][(qn) * 2 + n2] =                                      \
              __builtin_amdgcn_mfma_f32_16x16x32_bf16(                             \
                  Aq[m4 * 2 + kk], BREG[n2 * 2 + kk],                              \
                  acc[(qm) * 4 + m4][(qn) * 2 + n2], 0, 0, 0);                     \
    __builtin_amdgcn_s_setprio(0);

#define PH_PRE                                                                     \
    __builtin_amdgcn_sched_barrier(0);                                             \
    __builtin_amdgcn_s_barrier();                                                  \
    asm volatile("s_waitcnt lgkmcnt(0)" ::: "memory");                             \
    __builtin_amdgcn_sched_barrier(0);

// barrier kept ONLY at vmcnt phases (cross-wave drain visibility); VM==0 phases
// need no POST barrier (see derivation above).
#define PH_POST(VM)                                                                \
    if ((VM) == 4) { asm volatile("s_waitcnt vmcnt(4)" ::: "memory");              \
      __builtin_amdgcn_sched_barrier(0); __builtin_amdgcn_s_barrier(); }           \
    else if ((VM) == 1) { asm volatile("s_waitcnt vmcnt(0)" ::: "memory");         \
      __builtin_amdgcn_sched_barrier(0); __builtin_amdgcn_s_barrier(); }           \
    else { __builtin_amdgcn_sched_barrier(0); }

#define RD_A(buf, off)                                                             \
    _Pragma("unroll")                                                              \
    for (int m4 = 0; m4 < 4; m4++) {                                               \
      Aq[m4 * 2]     = *(const sh8*)(pA0 + (buf) * 32768 + (off) + m4 * 2048);     \
      Aq[m4 * 2 + 1] = *(const sh8*)(pA1 + (buf) * 32768 + (off) + m4 * 2048);     \
    }
#define RD_B(buf, off, BREG)                                                       \
    _Pragma("unroll")                                                              \
    for (int n2 = 0; n2 < 2; n2++) {                                               \
      BREG[n2 * 2]     = *(const sh8*)(pB0 + (buf) * 32768 + (off) + n2 * 2048);   \
      BREG[n2 * 2 + 1] = *(const sh8*)(pB1 + (buf) * 32768 + (off) + n2 * 2048);   \
    }

#define PH1(buf, STMT, VM) do { RD_A(buf, 0) RD_B(buf, 0, B0r)                     \
    STMT; PH_PRE MFMA_CL(0, 0, B0r) PH_POST(VM) } while (0)
#define PH2(buf, STMT, VM) do { RD_B(buf, 4096, B1r)                               \
    STMT; PH_PRE MFMA_CL(0, 1, B1r) PH_POST(VM) } while (0)
#define PH3(buf, STMT, VM) do { RD_A(buf, 8192)                                    \
    STMT; PH_PRE MFMA_CL(1, 1, B1r) PH_POST(VM) } while (0)
#define PH4(buf, STMT, VM) do {                                                    \
    STMT; PH_PRE MFMA_CL(1, 0, B0r) PH_POST(VM) } while (0)

// stage unit = 2 gload_lds16 per thread (16KB).
#define STAGE_A(tau, q) do {                                                       \
    int bo_ = ((tau) & 1) * 32768;                                                 \
    if constexpr (MODE == 0) {                                                     \
      const unsigned short* ap_ = A0p + ((tau) & 15) * 64;                         \
      gload_lds16(ap_ + oA##q##0, lds + lA + bo_ + (q) * 8192);                    \
      gload_lds16(ap_ + oA##q##1, lds + lA + bo_ + (q) * 8192 + 16384);            \
    } else {                                                                       \
      int kt_ = ((tau) < NTH) ? (tau) : (tau) - NTH;                               \
      const unsigned short* ap_ = (((tau) < NTH) ? H0p : H1p) +                    \
                                  (kt_ >> 2) * 65536 + (kt_ & 3) * 16384;          \
      gload_lds16(ap_ + fA##q##0, lds + lA + bo_ + (q) * 8192);                    \
      gload_lds16(ap_ + fA##q##1, lds + lA + bo_ + (q) * 8192 + 16384);            \
    } } while (0)

#define STAGE_B(tau, q) do {                                                       \
    int bo_ = ((tau) & 1) * 32768;                                                 \
    if constexpr (MODE == 0) {                                                     \
      const unsigned short* bp_ = w1tE +                                           \
          (size_t)(nbh8 + ((tau) >> 4)) * (256 * HH) + ((tau) & 15) * 64;          \
      gload_lds16(bp_ + oB##q##0, lds + lB + bo_ + (q) * 4096);                    \
      gload_lds16(bp_ + oB##q##1, lds + lB + bo_ + (q) * 4096 + 16384);            \
    } else {                                                                       \
      int kt_ = ((tau) < NTH) ? (tau) : (tau) - NTH;                               \
      const unsigned short* bp_ = (((tau) < NTH) ? B0p : B1p) + kt_ * 64;          \
      gload_lds16(bp_ + oB##q##0, lds + lB + bo_ + (q) * 4096);                    \
      gload_lds16(bp_ + oB##q##1, lds + lB + bo_ + (q) * 4096 + 16384);            \
    } } while (0)

#define STD8(T)                                                                    \
    PH1(0, { STAGE_A((T) + 1, 1); }, 0);                                           \
    PH2(0, { STAGE_B((T) + 1, 1); }, 0);                                           \
    PH3(0, { STAGE_A((T) + 2, 0); }, 0);                                           \
    PH4(0, { STAGE_B((T) + 2, 0); }, 4);                                           \
    PH1(1, { STAGE_A((T) + 2, 1); }, 0);                                           \
    PH2(1, { STAGE_B((T) + 2, 1); }, 0);                                           \
    PH3(1, { STAGE_A((T) + 3, 0); }, 0);                                           \
    PH4(1, { STAGE_B((T) + 3, 0); }, 4);

#define TAIL8(T)                                                                   \
    PH1(0, { STAGE_A((T) + 1, 1); }, 0);                                           \
    PH2(0, { STAGE_B((T) + 1, 1); }, 0);                                           \
    PH3(0, {}, 0);                                                                 \
    PH4(0, {}, 1);                                                                 \
    PH1(1, {}, 0);                                                                 \
    PH2(1, {}, 0);                                                                 \
    PH3(1, {}, 0);                                                                 \
    PH4(1, {}, 0);

template <int MODE>
__global__ __launch_bounds__(512, 1) void gemm8p(
    const unsigned short* __restrict__ XorH,   // MODE0: Xbf ; MODE1: hmid(v3)
    const unsigned short* __restrict__ Wt,     // MODE0: w1t ; MODE1: w2t(perm)
    const float* __restrict__ bias,            // MODE0: pb1 ; MODE1: pb2
    const int* __restrict__ re,
    const float* __restrict__ rw,
    unsigned short* __restrict__ hmid_out,     // MODE0 out (v3 layout)
    float* __restrict__ out) {                 // MODE1 out
  extern __shared__ char lds[];

  constexpr int NT  = 128;                         // total K-tiles (both modes)
  constexpr int NTH = (MODE == 0) ? NT : (FF / 64);// MODE1: expert switch at 64

  int P = blockIdx.x;
  int t = threadIdx.x;
  int lane = t & 63, wv = t >> 6;
  int wr = wv >> 2, wc = wv & 3;       // 2M x 4N waves
  int ln = lane & 15, kq = lane >> 4;

  const unsigned short *A0p = nullptr, *w1tE = nullptr;
  const unsigned short *H0p = nullptr, *H1p = nullptr, *B0p = nullptr, *B1p = nullptr;
  int pair = 0, b, e0 = 0, e1 = 0, mb, nb = 0, nbh8 = 0;
  int ldb;
  if constexpr (MODE == 0) {
    b = P & 7;                       // XCD <-> batch
    int k = P >> 3;                  // 0..31 per batch
    int pairbit = k & 1;
    mb = (k >> 1) & 7;
    nbh8 = (k >> 4) * 8;             // nb-half base (0 or 8)
    pair = b * 2 + pairbit;
    e0 = re[pair];
    A0p = XorH + (size_t)b * TT * HH + (size_t)mb * 256 * HH;  // fixed all segments
    w1tE = Wt + (size_t)e0 * FF * HH;
    ldb = HH;
  } else {
    b = P & 7;                       // XCD <-> batch
    int idx = P >> 3;
    nb = idx & 3; mb = idx >> 2;
    e0 = re[2 * b]; e1 = re[2 * b + 1];
    H0p = XorH + (size_t)(2 * b) * TT * FF + (size_t)mb * 16 * 65536;
    H1p = H0p + (size_t)TT * FF;
    B0p = Wt + (size_t)e0 * FF * HH + (size_t)nb * 256 * FF;
    B1p = Wt + (size_t)e1 * FF * HH + (size_t)nb * 256 * FF;
    ldb = FF;
  }

  // -------- precomputed per-lane addressing (loop-invariant) --------
  int lrow = t >> 3;                          // A stage row lane part (0..63)
  int lrB8 = (t >> 8) * 64 + ((t >> 3) & 31); // B stage row lane part
  int clel = ((t & 7) ^ ((t >> 3) & 7)) * 8;  // inverse-swizzled col (elements)
  // MODE0 A offsets (row-major Xbf, lda=HH)
  size_t oA00 = (size_t)(lrow)*HH + clel;
  size_t oA01 = (size_t)(128 + lrow) * HH + clel;
  size_t oA10 = (size_t)(64 + lrow) * HH + clel;
  size_t oA11 = (size_t)(192 + lrow) * HH + clel;
  // MODE1 A offsets (hmid v3: row*64 + col within [256][64] sub-tile) — contiguous.
  size_t fA00 = (size_t)(lrow)*64 + clel;
  size_t fA01 = (size_t)(128 + lrow) * 64 + clel;
  size_t fA10 = (size_t)(64 + lrow) * 64 + clel;
  size_t fA11 = (size_t)(192 + lrow) * 64 + clel;
  // B offsets (row-major Wt panels, ldb per mode)
  size_t oB00 = (size_t)(lrB8)*ldb + clel;
  size_t oB01 = (size_t)(128 + lrB8) * ldb + clel;
  size_t oB10 = (size_t)(32 + lrB8) * ldb + clel;
  size_t oB11 = (size_t)(160 + lrB8) * ldb + clel;
  // LDS stage dest lane bases (bytes)
  int lA = lrow * 128 + (t & 7) * 16;
  int lB = 65536 + lrB8 * 128 + (t & 7) * 16;
  // LDS read lane bases (bytes); row&7 == ln&7 for all fragment rows
  char* pA0 = lds + wr * 16384 + ln * 128 + ((kq ^ (ln & 7)) * 16);
  char* pA1 = lds + wr * 16384 + ln * 128 + (((4 + kq) ^ (ln & 7)) * 16);
  char* pB0 = lds + 65536 + wc * 8192 + ln * 128 + ((kq ^ (ln & 7)) * 16);
  char* pB1 = lds + 65536 + wc * 8192 + ln * 128 + (((4 + kq) ^ (ln & 7)) * 16);

  f32x4 acc[8][4];
#pragma unroll
  for (int m = 0; m < 8; m++)
#pragma unroll
    for (int n = 0; n < 4; n++) acc[m][n] = (f32x4){0.f, 0.f, 0.f, 0.f};

  sh8 Aq[8], B0r[4], B1r[4];

  // Prologue: tile0 fully (4 units), tile1 q0 (2 units). vmcnt(4)=2 units pending.
  STAGE_A(0, 0); STAGE_B(0, 0); STAGE_A(0, 1); STAGE_B(0, 1);
  STAGE_A(1, 0); STAGE_B(1, 0);
  asm volatile("s_waitcnt vmcnt(4)" ::: "memory");
  __builtin_amdgcn_sched_barrier(0);
  __builtin_amdgcn_s_barrier();

  if constexpr (MODE == 0) {
    float wgt = rw[pair];
    for (int seg = 0; seg < 8; ++seg) {
      int nIt = (seg == 7) ? 7 : 8;
      for (int it = 0; it < nIt; ++it) {
        int T = seg * 16 + it * 2;
        STD8(T);
      }
      if (seg == 7) { TAIL8(126); }
      // ----- segment epilogue: v3 packed 4B PLAIN stores (L2-absorbed) -----
      {
        int nbs = nbh8 + seg;
        float bbv[4];
#pragma unroll
        for (int nn = 0; nn < 4; nn++)
          bbv[nn] = bias[(size_t)e0 * FF + nbs * 256 + wc * 64 + nn * 16 + ln];
        // v3: logical f=nn*16+ln stored at c = (nn>>1)*32 + ln*2 + (nn&1).
        unsigned short* Cp = hmid_out + (size_t)pair * TT * FF +
                             (size_t)(mb * 16 + nbs) * 65536 + wc * 16384 +
                             (size_t)(wr * 128 + kq * 4) * 64 + ln * 2;
#pragma unroll
        for (int mm = 0; mm < 8; mm++) {
#pragma unroll
          for (int j = 0; j < 4; j++) {
            float gv[4];
#pragma unroll
            for (int nn = 0; nn < 4; nn++) {
              float v = acc[mm][nn][j] + bbv[nn];
              gv[nn] = wgt * (0.5f * v * (1.0f + erf_fast(v * 0.70710678118654752f)));
            }
            unsigned pk0 = (unsigned)f2bf(gv[0]) | ((unsigned)f2bf(gv[1]) << 16);
            unsigned pk1 = (unsigned)f2bf(gv[2]) | ((unsigned)f2bf(gv[3]) << 16);
            *(unsigned*)(Cp + (mm * 16 + j) * 64) = pk0;
            *(unsigned*)(Cp + (mm * 16 + j) * 64 + 32) = pk1;
          }
        }
#pragma unroll
        for (int m = 0; m < 8; m++)
#pragma unroll
          for (int n = 0; n < 4; n++) acc[m][n] = (f32x4){0.f, 0.f, 0.f, 0.f};
      }
    }
  } else {
    for (int T = 0; T + 2 < NT; T += 2) {
      STD8(T);
    }
    TAIL8(NT - 2);
    // ----- epilogue: out = acc + weighted bias (nt stores, standard layout) -----
    float w0 = rw[2 * b], w1v = rw[2 * b + 1];
#pragma unroll
    for (int nn = 0; nn < 4; nn++) {
      int col = nb * 256 + wc * 64 + nn * 16 + ln;
      float bv = w0 * bias[(size_t)e0 * HH + col] + w1v * bias[(size_t)e1 * HH + col];
#pragma unroll
      for (int mm = 0; mm < 8; mm++) {
#pragma unroll
        for (int j = 0; j < 4; j++) {
          int row = mb * 256 + wr * 128 + mm * 16 + kq * 4 + j;
          __builtin_nontemporal_store(acc[mm][nn][j] + bv,
              &out[(size_t)b * TT * HH + (size_t)row * HH + col]);
        }
      }
    }
  }
}

extern "C" void kernel_launch(void* const* d_in, const int* in_sizes, int n_in,
                              void* d_out, int out_size, void* d_ws, size_t ws_size,
                              hipStream_t stream) {
  const float* X  = (const float*)d_in[0];
  const float* gw = (const float*)d_in[1];
  const float* w1 = (const float*)d_in[2];
  const float* pb1 = (const float*)d_in[3];
  const float* w2 = (const float*)d_in[4];
  const float* pb2 = (const float*)d_in[5];
  float* out = (float*)d_out;

  char* ws = (char*)d_ws;
  int* re = (int*)ws;                     // 16 ints
  float* rw = (float*)(ws + 64);          // 16 floats
  float* partial = (float*)(ws + 256);    // [B][16][H] f32 = 512KB
  unsigned short* Xbf = (unsigned short*)(ws + 256 + 524288);  // [B][T][H] bf16 = 32MB
  const size_t fixed = 256 + 524288 + (size_t)BB * TT * HH * 2;

  unsigned short* w1t = (unsigned short*)(ws + fixed);                          // 64MB
  unsigned short* w2t = (unsigned short*)(ws + fixed + (size_t)EE * HH * FF * 2);
  unsigned short* hmid = (unsigned short*)(ws + fixed + (size_t)2 * EE * HH * FF * 2); // 256MB

  hipFuncSetAttribute((const void*)gemm8p<0>,
                      hipFuncAttributeMaxDynamicSharedMemorySize, 131072);
  hipFuncSetAttribute((const void*)gemm8p<1>,
                      hipFuncAttributeMaxDynamicSharedMemorySize, 131072);

  prep<<<dim3(16, BB), 256, 0, stream>>>(X, Xbf, partial);
  gating_kernel<<<BB, 256, 0, stream>>>(partial, gw, re, rw);

  transposeE<<<dim3(HH / 64, FF / 64, EE), 256, 0, stream>>>(w1, w1t, re, HH, FF, 0);
  transposeE<<<dim3(FF / 64, HH / 64, EE), 256, 0, stream>>>(w2, w2t, re, FF, HH, 1);

  gemm8p<0><<<256, 512, 131072, stream>>>(Xbf, w1t, pb1, re, rw, hmid, nullptr);
  gemm8p<1><<<256, 512, 131072, stream>>>(hmid, w2t, pb2, re, rw, nullptr, out);
}

// Round 16
// 618.423 us; speedup vs baseline: 2.1452x; 1.0144x over previous
//
#include <hip/hip_runtime.h>
#include <hip/hip_bf16.h>
#include <math.h>

// Problem constants
#define BB 8
#define TT 2048
#define HH 1024
#define FF 4096
#define EE 8

typedef __attribute__((ext_vector_type(8))) short sh8;   // 8 bf16 (4 VGPRs)
typedef __attribute__((ext_vector_type(4))) short sh4;   // 4 bf16 (8B)
typedef __attribute__((ext_vector_type(4))) float f32x4; // MFMA acc
typedef __attribute__((ext_vector_type(4))) float f4;

__device__ inline unsigned short f2bf(float f) {
  unsigned u = __builtin_bit_cast(unsigned, f);
  u += 0x7FFFu + ((u >> 16) & 1u);
  return (unsigned short)(u >> 16);
}

// A&S 7.1.25 erf approximation, |err| <= 2.5e-5, branchless (3-term).
// Refchecked R13/R14/R15 (absmax 0.0039, identical to 5-term).
__device__ inline float erf_fast(float x) {
  float ax = fabsf(x);
  float t = 1.0f / (1.0f + 0.47047f * ax);
  float y = t * (0.3480242f + t * (-0.0958798f + t * 0.7478556f));
  float e = __expf(-ax * ax);
  float r = 1.0f - y * e;
  return copysignf(r, x);
}

// async global->LDS, 16B per lane, wave-uniform LDS base + lane*16
__device__ inline void gload_lds16(const void* g, void* l) {
  __builtin_amdgcn_global_load_lds(
      (const __attribute__((address_space(1))) unsigned int*)g,
      (__attribute__((address_space(3))) unsigned int*)l, 16, 0, 0);
}

// ---------------- fused: X f32 -> bf16 AND per-chunk column partial sums ----------------
__global__ __launch_bounds__(256) void prep(const float* __restrict__ X,
                                            unsigned short* __restrict__ Xb,
                                            float* __restrict__ partial) {
  int tc = blockIdx.x, b = blockIdx.y, t = threadIdx.x;
  const float* src = X + ((size_t)b * TT + (size_t)tc * 128) * HH;
  unsigned short* dst = Xb + ((size_t)b * TT + (size_t)tc * 128) * HH;
  f4 s = {0.f, 0.f, 0.f, 0.f};
  for (int r = 0; r < 128; ++r) {
    f4 v = *(const f4*)&src[(size_t)r * HH + t * 4];
    s[0] += v[0]; s[1] += v[1]; s[2] += v[2]; s[3] += v[3];
    sh4 o;
    o[0] = (short)f2bf(v[0]); o[1] = (short)f2bf(v[1]);
    o[2] = (short)f2bf(v[2]); o[3] = (short)f2bf(v[3]);
    *(sh4*)&dst[(size_t)r * HH + t * 4] = o;
  }
  *(f4*)&partial[((size_t)b * 16 + tc) * HH + t * 4] = s;
}

// ---------------- gating: logits -> softmax -> top2 -> routing ----------------
__global__ __launch_bounds__(256) void gating_kernel(const float* __restrict__ partial,
                                                     const float* __restrict__ gw,
                                                     int* __restrict__ re,
                                                     float* __restrict__ rw) {
  int b = blockIdx.x, t = threadIdx.x;
  float acc[EE];
#pragma unroll
  for (int e = 0; e < EE; e++) acc[e] = 0.f;
  for (int jj = 0; jj < 4; jj++) {
    int h = t + jj * 256;
    float s = 0.f;
    for (int tc = 0; tc < 16; tc++) s += partial[((size_t)b * 16 + tc) * HH + h];
    s *= (1.0f / (float)TT);
#pragma unroll
    for (int e = 0; e < EE; e++) acc[e] += s * gw[h * EE + e];
  }
#pragma unroll
  for (int off = 32; off >= 1; off >>= 1) {
#pragma unroll
    for (int e = 0; e < EE; e++) acc[e] += __shfl_down(acc[e], off);
  }
  __shared__ float red[4][EE];
  if ((t & 63) == 0) {
#pragma unroll
    for (int e = 0; e < EE; e++) red[t >> 6][e] = acc[e];
  }
  __syncthreads();
  if (t == 0) {
    float lg[EE];
#pragma unroll
    for (int e = 0; e < EE; e++) lg[e] = red[0][e] + red[1][e] + red[2][e] + red[3][e];
    float mx = lg[0];
#pragma unroll
    for (int e = 1; e < EE; e++) mx = fmaxf(mx, lg[e]);
    float p[EE]; float s = 0.f;
#pragma unroll
    for (int e = 0; e < EE; e++) { p[e] = expf(lg[e] - mx); s += p[e]; }
#pragma unroll
    for (int e = 0; e < EE; e++) p[e] /= s;
    int i1 = 0;
#pragma unroll
    for (int e = 1; e < EE; e++) if (p[e] > p[i1]) i1 = e;  // first index wins ties
    int i2 = -1;
#pragma unroll
    for (int e = 0; e < EE; e++) {
      if (e == i1) continue;
      if (i2 < 0 || p[e] > p[i2]) i2 = e;
    }
    float den = p[i1] + p[i2];
    re[b * 2 + 0] = i1; rw[b * 2 + 0] = p[i1] / den;
    re[b * 2 + 1] = i2; rw[b * 2 + 1] = p[i2] / den;
  }
}

// ---------------- transpose+convert per-EXPERT weights: W[e][K][N] f32 -> Wt[e][N][K] bf16
// perm=1 (w2): within each K-32 block, stored position c holds logical
// k = (c&32) + (c&1)*16 + ((c>>1)&15) — matching hmid v3's f-permutation so the
// MFMA K-order is consistent between A (hmid) and B (w2t) in MODE1.
__global__ __launch_bounds__(256) void transposeE(const float* __restrict__ W,
                                                  unsigned short* __restrict__ Wt,
                                                  const int* __restrict__ re,
                                                  int K, int N, int perm) {
  int e = blockIdx.z;
  bool u = false;
#pragma unroll
  for (int p = 0; p < 16; p++) u = u || (re[p] == e);
  if (!u) return;

  __shared__ float tile[64][65];
  int kb = blockIdx.x, nb = blockIdx.y;
  const float* src = W + (size_t)e * K * N + (size_t)(kb * 64) * N + nb * 64;
  int t = threadIdx.x;
#pragma unroll
  for (int pass = 0; pass < 4; pass++) {
    int r = (t >> 4) + pass * 16;
    int c = (t & 15) * 4;
    *(f4*)&tile[r][c] = *(const f4*)&src[(size_t)r * N + c];
  }
  __syncthreads();
#pragma unroll
  for (int pass = 0; pass < 2; pass++) {
    int idx = (t + pass * 256) * 8;
    int nl = idx >> 6, k0 = idx & 63;
    sh8 o;
    if (perm) {
#pragma unroll
      for (int j = 0; j < 8; j++) {
        int local = (k0 & 31) + j;
        int kk = (k0 & 32) + ((local & 1) << 4) + (local >> 1);
        o[j] = (short)f2bf(tile[kk][nl]);
      }
    } else {
#pragma unroll
      for (int j = 0; j < 8; j++) o[j] = (short)f2bf(tile[k0 + j][nl]);
    }
    *(sh8*)&Wt[(size_t)e * N * K + (size_t)(nb * 64 + nl) * K + kb * 64 + k0] = o;
  }
}

// ================= 256x256 8-phase counted-vmcnt GEMM (T1+T2+T3+T4+T5) =================
// R16 = R15 with the remaining redundant PRE barriers removed. Minimal barrier set
// (4 per tile-pair), derived from the full hazard graph:
//   ph2-PRE + ph6-PRE barriers: write-after-read — ph3/ph4 STAGE into buf rows read
//     at ph1 (reader's lgkmcnt(0) precedes its ph2-PRE barrier; writer's STAGE issue
//     follows it), resp. ph7/ph8 STAGE vs ph5 reads via ph6-PRE.
//   ph4/ph8 POST vmcnt(4)+barrier: read-after-write — at ph4, 12 loads outstanding,
//     vmcnt(4) spares exactly tile T+2's q0 units and drains all of tile T+1 (read
//     in ph5-8); same at ph8 one tile later. Writes at ph5/ph6 vs reads at ph3/ph2
//     are also covered by the ph4 barrier.
//   lgkmcnt(0) retained EVERY phase (own ds_read->MFMA dep) + sched_barrier pinning.
// hmid v3 (elements, per pair): (mb*16+f256)*65536 + wc*16384 + row*64 + c, where
//   logical f = nn*16+ln stored at c = (nn>>1)*32 + ln*2 + (nn&1); w2t carries the
//   identical K-permutation (transposeE perm=1). MODE1 stage reads 1KB contiguous.
// MODE 0 (PERSISTENT): grid 256, block = (pair, mb, nbhalf); 8 nb-segments with a
//   continuous K-pipeline; per-segment serial epilogue (plain packed 4B stores);
//   acc re-zeroed per segment. [Epilogue-hiding attempts R9/R10/R13 all regressed
//   via scratch spill — nothing consuming acc or storing may live in the K-loop.]
// MODE 1: out[b] = hmid-pair-concat (K) @ w2t^T + weighted b2.
// LDS 128KB: A[2][256][64] + B[2][256][64] bf16, XOR swizzle byte ^= (row&7)<<4 via
//   inverse-swizzled GLOBAL SOURCE + swizzled ds_read. Frags read ONCE per tile (24).
// vmcnt ledger: prologue 12 issued, vmcnt(4); steady vmcnt(4) at phases 4/8; final
//   tail stages only tile NT-1 q1 and uses vmcnt(0) at phase 4.

#define MFMA_CL(qm, qn, BREG)                                                      \
    __builtin_amdgcn_s_setprio(1);                                                 \
    _Pragma("unroll")                                                              \
    for (int m4 = 0; m4 < 4; m4++)                                                 \
      _Pragma("unroll")                                                            \
      for (int n2 = 0; n2 < 2; n2++)                                               \
        _Pragma("unroll")                                                          \
        for (int kk = 0; kk < 2; kk++)                                             \
          acc[(qm) * 4 + m4][(qn) * 2 + n2] =                                      \
              __builtin_amdgcn_mfma_f32_16x16x32_bf16(                             \
                  Aq[m4 * 2 + kk], BREG[n2 * 2 + kk],                              \
                  acc[(qm) * 4 + m4][(qn) * 2 + n2], 0, 0, 0);                     \
    __builtin_amdgcn_s_setprio(0);

// PRE with barrier (phases 2 and 6 only — write-after-read ordering)
#define PH_PRE_B                                                                   \
    __builtin_amdgcn_sched_barrier(0);                                             \
    __builtin_amdgcn_s_barrier();                                                  \
    asm volatile("s_waitcnt lgkmcnt(0)" ::: "memory");                             \
    __builtin_amdgcn_sched_barrier(0);

// PRE without barrier (own-data lgkmcnt only)
#define PH_PRE_N                                                                   \
    __builtin_amdgcn_sched_barrier(0);                                             \
    asm volatile("s_waitcnt lgkmcnt(0)" ::: "memory");                             \
    __builtin_amdgcn_sched_barrier(0);

// barrier kept ONLY at vmcnt phases (cross-wave drain visibility)
#define PH_POST(VM)                                                                \
    if ((VM) == 4) { asm volatile("s_waitcnt vmcnt(4)" ::: "memory");              \
      __builtin_amdgcn_sched_barrier(0); __builtin_amdgcn_s_barrier(); }           \
    else if ((VM) == 1) { asm volatile("s_waitcnt vmcnt(0)" ::: "memory");         \
      __builtin_amdgcn_sched_barrier(0); __builtin_amdgcn_s_barrier(); }           \
    else { __builtin_amdgcn_sched_barrier(0); }

#define RD_A(buf, off)                                                             \
    _Pragma("unroll")                                                              \
    for (int m4 = 0; m4 < 4; m4++) {                                               \
      Aq[m4 * 2]     = *(const sh8*)(pA0 + (buf) * 32768 + (off) + m4 * 2048);     \
      Aq[m4 * 2 + 1] = *(const sh8*)(pA1 + (buf) * 32768 + (off) + m4 * 2048);     \
    }
#define RD_B(buf, off, BREG)                                                       \
    _Pragma("unroll")                                                              \
    for (int n2 = 0; n2 < 2; n2++) {                                               \
      BREG[n2 * 2]     = *(const sh8*)(pB0 + (buf) * 32768 + (off) + n2 * 2048);   \
      BREG[n2 * 2 + 1] = *(const sh8*)(pB1 + (buf) * 32768 + (off) + n2 * 2048);   \
    }

#define PH1(buf, STMT, VM) do { RD_A(buf, 0) RD_B(buf, 0, B0r)                     \
    STMT; PH_PRE_N MFMA_CL(0, 0, B0r) PH_POST(VM) } while (0)
#define PH2(buf, STMT, VM) do { RD_B(buf, 4096, B1r)                               \
    STMT; PH_PRE_B MFMA_CL(0, 1, B1r) PH_POST(VM) } while (0)
#define PH3(buf, STMT, VM) do { RD_A(buf, 8192)                                    \
    STMT; PH_PRE_N MFMA_CL(1, 1, B1r) PH_POST(VM) } while (0)
#define PH4(buf, STMT, VM) do {                                                    \
    STMT; PH_PRE_N MFMA_CL(1, 0, B0r) PH_POST(VM) } while (0)

// stage unit = 2 gload_lds16 per thread (16KB).
#define STAGE_A(tau, q) do {                                                       \
    int bo_ = ((tau) & 1) * 32768;                                                 \
    if constexpr (MODE == 0) {                                                     \
      const unsigned short* ap_ = A0p + ((tau) & 15) * 64;                         \
      gload_lds16(ap_ + oA##q##0, lds + lA + bo_ + (q) * 8192);                    \
      gload_lds16(ap_ + oA##q##1, lds + lA + bo_ + (q) * 8192 + 16384);            \
    } else {                                                                       \
      int kt_ = ((tau) < NTH) ? (tau) : (tau) - NTH;                               \
      const unsigned short* ap_ = (((tau) < NTH) ? H0p : H1p) +                    \
                                  (kt_ >> 2) * 65536 + (kt_ & 3) * 16384;          \
      gload_lds16(ap_ + fA##q##0, lds + lA + bo_ + (q) * 8192);                    \
      gload_lds16(ap_ + fA##q##1, lds + lA + bo_ + (q) * 8192 + 16384);            \
    } } while (0)

#define STAGE_B(tau, q) do {                                                       \
    int bo_ = ((tau) & 1) * 32768;                                                 \
    if constexpr (MODE == 0) {                                                     \
      const unsigned short* bp_ = w1tE +                                           \
          (size_t)(nbh8 + ((tau) >> 4)) * (256 * HH) + ((tau) & 15) * 64;          \
      gload_lds16(bp_ + oB##q##0, lds + lB + bo_ + (q) * 4096);                    \
      gload_lds16(bp_ + oB##q##1, lds + lB + bo_ + (q) * 4096 + 16384);            \
    } else {                                                                       \
      int kt_ = ((tau) < NTH) ? (tau) : (tau) - NTH;                               \
      const unsigned short* bp_ = (((tau) < NTH) ? B0p : B1p) + kt_ * 64;          \
      gload_lds16(bp_ + oB##q##0, lds + lB + bo_ + (q) * 4096);                    \
      gload_lds16(bp_ + oB##q##1, lds + lB + bo_ + (q) * 4096 + 16384);            \
    } } while (0)

#define STD8(T)                                                                    \
    PH1(0, { STAGE_A((T) + 1, 1); }, 0);                                           \
    PH2(0, { STAGE_B((T) + 1, 1); }, 0);                                           \
    PH3(0, { STAGE_A((T) + 2, 0); }, 0);                                           \
    PH4(0, { STAGE_B((T) + 2, 0); }, 4);                                           \
    PH1(1, { STAGE_A((T) + 2, 1); }, 0);                                           \
    PH2(1, { STAGE_B((T) + 2, 1); }, 0);                                           \
    PH3(1, { STAGE_A((T) + 3, 0); }, 0);                                           \
    PH4(1, { STAGE_B((T) + 3, 0); }, 4);

#define TAIL8(T)                                                                   \
    PH1(0, { STAGE_A((T) + 1, 1); }, 0);                                           \
    PH2(0, { STAGE_B((T) + 1, 1); }, 0);                                           \
    PH3(0, {}, 0);                                                                 \
    PH4(0, {}, 1);                                                                 \
    PH1(1, {}, 0);                                                                 \
    PH2(1, {}, 0);                                                                 \
    PH3(1, {}, 0);                                                                 \
    PH4(1, {}, 0);

template <int MODE>
__global__ __launch_bounds__(512, 1) void gemm8p(
    const unsigned short* __restrict__ XorH,   // MODE0: Xbf ; MODE1: hmid(v3)
    const unsigned short* __restrict__ Wt,     // MODE0: w1t ; MODE1: w2t(perm)
    const float* __restrict__ bias,            // MODE0: pb1 ; MODE1: pb2
    const int* __restrict__ re,
    const float* __restrict__ rw,
    unsigned short* __restrict__ hmid_out,     // MODE0 out (v3 layout)
    float* __restrict__ out) {                 // MODE1 out
  extern __shared__ char lds[];

  constexpr int NT  = 128;                         // total K-tiles (both modes)
  constexpr int NTH = (MODE == 0) ? NT : (FF / 64);// MODE1: expert switch at 64

  int P = blockIdx.x;
  int t = threadIdx.x;
  int lane = t & 63, wv = t >> 6;
  int wr = wv >> 2, wc = wv & 3;       // 2M x 4N waves
  int ln = lane & 15, kq = lane >> 4;

  const unsigned short *A0p = nullptr, *w1tE = nullptr;
  const unsigned short *H0p = nullptr, *H1p = nullptr, *B0p = nullptr, *B1p = nullptr;
  int pair = 0, b, e0 = 0, e1 = 0, mb, nb = 0, nbh8 = 0;
  int ldb;
  if constexpr (MODE == 0) {
    b = P & 7;                       // XCD <-> batch
    int k = P >> 3;                  // 0..31 per batch
    int pairbit = k & 1;
    mb = (k >> 1) & 7;
    nbh8 = (k >> 4) * 8;             // nb-half base (0 or 8)
    pair = b * 2 + pairbit;
    e0 = re[pair];
    A0p = XorH + (size_t)b * TT * HH + (size_t)mb * 256 * HH;  // fixed all segments
    w1tE = Wt + (size_t)e0 * FF * HH;
    ldb = HH;
  } else {
    b = P & 7;                       // XCD <-> batch
    int idx = P >> 3;
    nb = idx & 3; mb = idx >> 2;
    e0 = re[2 * b]; e1 = re[2 * b + 1];
    H0p = XorH + (size_t)(2 * b) * TT * FF + (size_t)mb * 16 * 65536;
    H1p = H0p + (size_t)TT * FF;
    B0p = Wt + (size_t)e0 * FF * HH + (size_t)nb * 256 * FF;
    B1p = Wt + (size_t)e1 * FF * HH + (size_t)nb * 256 * FF;
    ldb = FF;
  }

  // -------- precomputed per-lane addressing (loop-invariant) --------
  int lrow = t >> 3;                          // A stage row lane part (0..63)
  int lrB8 = (t >> 8) * 64 + ((t >> 3) & 31); // B stage row lane part
  int clel = ((t & 7) ^ ((t >> 3) & 7)) * 8;  // inverse-swizzled col (elements)
  // MODE0 A offsets (row-major Xbf, lda=HH)
  size_t oA00 = (size_t)(lrow)*HH + clel;
  size_t oA01 = (size_t)(128 + lrow) * HH + clel;
  size_t oA10 = (size_t)(64 + lrow) * HH + clel;
  size_t oA11 = (size_t)(192 + lrow) * HH + clel;
  // MODE1 A offsets (hmid v3: row*64 + col within [256][64] sub-tile) — contiguous.
  size_t fA00 = (size_t)(lrow)*64 + clel;
  size_t fA01 = (size_t)(128 + lrow) * 64 + clel;
  size_t fA10 = (size_t)(64 + lrow) * 64 + clel;
  size_t fA11 = (size_t)(192 + lrow) * 64 + clel;
  // B offsets (row-major Wt panels, ldb per mode)
  size_t oB00 = (size_t)(lrB8)*ldb + clel;
  size_t oB01 = (size_t)(128 + lrB8) * ldb + clel;
  size_t oB10 = (size_t)(32 + lrB8) * ldb + clel;
  size_t oB11 = (size_t)(160 + lrB8) * ldb + clel;
  // LDS stage dest lane bases (bytes)
  int lA = lrow * 128 + (t & 7) * 16;
  int lB = 65536 + lrB8 * 128 + (t & 7) * 16;
  // LDS read lane bases (bytes); row&7 == ln&7 for all fragment rows
  char* pA0 = lds + wr * 16384 + ln * 128 + ((kq ^ (ln & 7)) * 16);
  char* pA1 = lds + wr * 16384 + ln * 128 + (((4 + kq) ^ (ln & 7)) * 16);
  char* pB0 = lds + 65536 + wc * 8192 + ln * 128 + ((kq ^ (ln & 7)) * 16);
  char* pB1 = lds + 65536 + wc * 8192 + ln * 128 + (((4 + kq) ^ (ln & 7)) * 16);

  f32x4 acc[8][4];
#pragma unroll
  for (int m = 0; m < 8; m++)
#pragma unroll
    for (int n = 0; n < 4; n++) acc[m][n] = (f32x4){0.f, 0.f, 0.f, 0.f};

  sh8 Aq[8], B0r[4], B1r[4];

  // Prologue: tile0 fully (4 units), tile1 q0 (2 units). vmcnt(4)=2 units pending.
  STAGE_A(0, 0); STAGE_B(0, 0); STAGE_A(0, 1); STAGE_B(0, 1);
  STAGE_A(1, 0); STAGE_B(1, 0);
  asm volatile("s_waitcnt vmcnt(4)" ::: "memory");
  __builtin_amdgcn_sched_barrier(0);
  __builtin_amdgcn_s_barrier();

  if constexpr (MODE == 0) {
    float wgt = rw[pair];
    for (int seg = 0; seg < 8; ++seg) {
      int nIt = (seg == 7) ? 7 : 8;
      for (int it = 0; it < nIt; ++it) {
        int T = seg * 16 + it * 2;
        STD8(T);
      }
      if (seg == 7) { TAIL8(126); }
      // ----- segment epilogue: v3 packed 4B PLAIN stores (L2-absorbed) -----
      {
        int nbs = nbh8 + seg;
        float bbv[4];
#pragma unroll
        for (int nn = 0; nn < 4; nn++)
          bbv[nn] = bias[(size_t)e0 * FF + nbs * 256 + wc * 64 + nn * 16 + ln];
        // v3: logical f=nn*16+ln stored at c = (nn>>1)*32 + ln*2 + (nn&1).
        unsigned short* Cp = hmid_out + (size_t)pair * TT * FF +
                             (size_t)(mb * 16 + nbs) * 65536 + wc * 16384 +
                             (size_t)(wr * 128 + kq * 4) * 64 + ln * 2;
#pragma unroll
        for (int mm = 0; mm < 8; mm++) {
#pragma unroll
          for (int j = 0; j < 4; j++) {
            float gv[4];
#pragma unroll
            for (int nn = 0; nn < 4; nn++) {
              float v = acc[mm][nn][j] + bbv[nn];
              gv[nn] = wgt * (0.5f * v * (1.0f + erf_fast(v * 0.70710678118654752f)));
            }
            unsigned pk0 = (unsigned)f2bf(gv[0]) | ((unsigned)f2bf(gv[1]) << 16);
            unsigned pk1 = (unsigned)f2bf(gv[2]) | ((unsigned)f2bf(gv[3]) << 16);
            *(unsigned*)(Cp + (mm * 16 + j) * 64) = pk0;
            *(unsigned*)(Cp + (mm * 16 + j) * 64 + 32) = pk1;
          }
        }
#pragma unroll
        for (int m = 0; m < 8; m++)
#pragma unroll
          for (int n = 0; n < 4; n++) acc[m][n] = (f32x4){0.f, 0.f, 0.f, 0.f};
      }
    }
  } else {
    for (int T = 0; T + 2 < NT; T += 2) {
      STD8(T);
    }
    TAIL8(NT - 2);
    // ----- epilogue: out = acc + weighted bias (nt stores, standard layout) -----
    float w0 = rw[2 * b], w1v = rw[2 * b + 1];
#pragma unroll
    for (int nn = 0; nn < 4; nn++) {
      int col = nb * 256 + wc * 64 + nn * 16 + ln;
      float bv = w0 * bias[(size_t)e0 * HH + col] + w1v * bias[(size_t)e1 * HH + col];
#pragma unroll
      for (int mm = 0; mm < 8; mm++) {
#pragma unroll
        for (int j = 0; j < 4; j++) {
          int row = mb * 256 + wr * 128 + mm * 16 + kq * 4 + j;
          __builtin_nontemporal_store(acc[mm][nn][j] + bv,
              &out[(size_t)b * TT * HH + (size_t)row * HH + col]);
        }
      }
    }
  }
}

extern "C" void kernel_launch(void* const* d_in, const int* in_sizes, int n_in,
                              void* d_out, int out_size, void* d_ws, size_t ws_size,
                              hipStream_t stream) {
  const float* X  = (const float*)d_in[0];
  const float* gw = (const float*)d_in[1];
  const float* w1 = (const float*)d_in[2];
  const float* pb1 = (const float*)d_in[3];
  const float* w2 = (const float*)d_in[4];
  const float* pb2 = (const float*)d_in[5];
  float* out = (float*)d_out;

  char* ws = (char*)d_ws;
  int* re = (int*)ws;                     // 16 ints
  float* rw = (float*)(ws + 64);          // 16 floats
  float* partial = (float*)(ws + 256);    // [B][16][H] f32 = 512KB
  unsigned short* Xbf = (unsigned short*)(ws + 256 + 524288);  // [B][T][H] bf16 = 32MB
  const size_t fixed = 256 + 524288 + (size_t)BB * TT * HH * 2;

  unsigned short* w1t = (unsigned short*)(ws + fixed);                          // 64MB
  unsigned short* w2t = (unsigned short*)(ws + fixed + (size_t)EE * HH * FF * 2);
  unsigned short* hmid = (unsigned short*)(ws + fixed + (size_t)2 * EE * HH * FF * 2); // 256MB

  hipFuncSetAttribute((const void*)gemm8p<0>,
                      hipFuncAttributeMaxDynamicSharedMemorySize, 131072);
  hipFuncSetAttribute((const void*)gemm8p<1>,
                      hipFuncAttributeMaxDynamicSharedMemorySize, 131072);

  prep<<<dim3(16, BB), 256, 0, stream>>>(X, Xbf, partial);
  gating_kernel<<<BB, 256, 0, stream>>>(partial, gw, re, rw);

  transposeE<<<dim3(HH / 64, FF / 64, EE), 256, 0, stream>>>(w1, w1t, re, HH, FF, 0);
  transposeE<<<dim3(FF / 64, HH / 64, EE), 256, 0, stream>>>(w2, w2t, re, FF, HH, 1);

  gemm8p<0><<<256, 512, 131072, stream>>>(Xbf, w1t, pb1, re, rw, hmid, nullptr);
  gemm8p<1><<<256, 512, 131072, stream>>>(hmid, w2t, pb2, re, rw, nullptr, out);
}